// Round 1
// baseline (522.835 us; speedup 1.0000x reference)
//
#include <hip/hip_runtime.h>
#include <math.h>

// Problem constants
#define N_TOK 131072   // 32*64*64 tokens
#define D     64       // embedding dim
#define K     1024     // codebook size

// Output layout (floats, concatenated in reference return order):
#define OUT_LOSS  8388608
#define OUT_IDX   8388609
#define OUT_PERP  8519681

// ws layout (bytes):
//   0        counts  u32[1024]
//   4096     enorm   f32[1024]  np-exact ||e||^2
//   8192     sinit   f32[1024]  fp64-accurate ||e||^2 (screen C-init)
//   12288    sse     f32
//   12292    rcnt    u32        rescue-list counter
//   16384    w_hi    s16[65536] bf16 hi split of w (128 KB)
//   147456   w_lo    s16[65536] bf16 lo split of w (128 KB)
//   278528   m1s     f32[2][131072] per-half best dist      (1 MB)
//   1327104  m2s     f32[2][131072] per-half 2nd-best dist  (1 MB)
//   2375680  i1s     i32[2][131072] per-half best index     (1 MB)
//   3424256  rlist   i32[131072] compacted rescue token ids (512 KB)

#define W_WINDOW 1e-4f

typedef short bf16x8 __attribute__((ext_vector_type(8)));
typedef float f32x4  __attribute__((ext_vector_type(4)));
typedef float vf16   __attribute__((ext_vector_type(16)));

// ---------------------------------------------------------------------------
__device__ __forceinline__ float np_pairsum64(const float* sq) {
    float r[8];
#pragma unroll
    for (int j = 0; j < 8; ++j) r[j] = sq[j];
#pragma unroll
    for (int i = 8; i < 64; i += 8) {
#pragma unroll
        for (int j = 0; j < 8; ++j) r[j] = __fadd_rn(r[j], sq[i + j]);
    }
    return __fadd_rn(
        __fadd_rn(__fadd_rn(r[0], r[1]), __fadd_rn(r[2], r[3])),
        __fadd_rn(__fadd_rn(r[4], r[5]), __fadd_rn(r[6], r[7])));
}

__device__ __forceinline__ short bf16_trunc(float f) {
    return (short)(__float_as_uint(f) >> 16);
}
__device__ __forceinline__ float bf16_up(short s) {
    return __uint_as_float(((unsigned)(unsigned short)s) << 16);
}

// ---------------------------------------------------------------------------
__global__ void vq_prep(const float* __restrict__ w,
                        float* __restrict__ enorm,
                        float* __restrict__ sinit,
                        short* __restrict__ w_hi,
                        short* __restrict__ w_lo,
                        unsigned* __restrict__ counts,
                        float* __restrict__ sse,
                        unsigned* __restrict__ rcnt) {
    int k = blockIdx.x * blockDim.x + threadIdx.x;
    if (k < K) {
        const float* wr = w + (size_t)k * D;
        float sq[D];
        double acc = 0.0;
#pragma unroll
        for (int i = 0; i < D; ++i) {
            float v = wr[i];
            sq[i] = __fmul_rn(v, v);
            acc += (double)v * (double)v;
            short hi = bf16_trunc(v);
            float res = v - bf16_up(hi);
            short lo = bf16_trunc(res);
            w_hi[(size_t)k * D + i] = hi;
            w_lo[(size_t)k * D + i] = lo;
        }
        enorm[k] = np_pairsum64(sq);
        sinit[k] = (float)acc;
        counts[k] = 0u;
    }
    if (k == 0) { *sse = 0.f; *rcnt = 0u; }
}

// ---------------------------------------------------------------------------
// Screen, split-K: blockIdx.y = half selects code tiles [half*32, half*32+32).
// Per-half math is identical (ascending tiles, strict-< first-min); the exact
// merge happens in vq_epi. 2x wave count -> occupancy cap 50% -> 100%.
// ---------------------------------------------------------------------------
#define MFMA(A, B, C) __builtin_amdgcn_mfma_f32_16x16x32_bf16(A, B, C, 0, 0, 0)

__global__ __launch_bounds__(256, 8)
void vq_screen(const float* __restrict__ x,
               const float* __restrict__ sinit,
               const short* __restrict__ w_hi,
               const short* __restrict__ w_lo,
               float* __restrict__ m1s,
               float* __restrict__ m2s,
               int* __restrict__ i1s) {
    const int lane = threadIdx.x & 63;
    const int wv   = __builtin_amdgcn_readfirstlane(threadIdx.x >> 6);
    const int quad = lane >> 4;
    const int col  = lane & 15;
    const int tokWave = blockIdx.x * 128 + wv * 32;
    const int half = blockIdx.y;           // 0: codes 0..511, 1: codes 512..1023
    const int t0 = half * 32;

    bf16x8 Ah[2][2], Al[2][2];
#pragma unroll
    for (int mt = 0; mt < 2; ++mt) {
#pragma unroll
        for (int ks = 0; ks < 2; ++ks) {
            const float4* ap = (const float4*)(x + (size_t)(tokWave + mt * 16 + col) * D
                                               + ks * 32 + quad * 8);
            float4 u0 = ap[0], u1 = ap[1];
            float f[8] = {u0.x, u0.y, u0.z, u0.w, u1.x, u1.y, u1.z, u1.w};
            bf16x8 h, l;
#pragma unroll
            for (int j = 0; j < 8; ++j) {
                float v = -2.0f * f[j];
                short hi = bf16_trunc(v);
                float res = v - bf16_up(hi);
                h[j] = hi;
                l[j] = bf16_trunc(res);
            }
            Ah[mt][ks] = h;
            Al[mt][ks] = l;
        }
    }

    float m1[8], m2[8];
    int   i1[8];
#pragma unroll
    for (int s = 0; s < 8; ++s) { m1[s] = INFINITY; m2[s] = INFINITY; i1[s] = 0; }

    for (int tile = t0; tile < t0 + 32; ++tile) {
        const int cbase = tile * 16;
        const size_t rowoff = (size_t)(cbase + col) * D;
        bf16x8 Bh0 = *(const bf16x8*)(w_hi + rowoff + 0 * 32 + quad * 8);
        bf16x8 Bh1 = *(const bf16x8*)(w_hi + rowoff + 1 * 32 + quad * 8);
        bf16x8 Bl0 = *(const bf16x8*)(w_lo + rowoff + 0 * 32 + quad * 8);
        bf16x8 Bl1 = *(const bf16x8*)(w_lo + rowoff + 1 * 32 + quad * 8);
        float si = sinit[cbase + col];
        f32x4 C0 = {si, si, si, si};
        f32x4 C1 = {si, si, si, si};
        C0 = MFMA(Ah[0][0], Bh0, C0); C0 = MFMA(Ah[0][1], Bh1, C0);
        C0 = MFMA(Ah[0][0], Bl0, C0); C0 = MFMA(Ah[0][1], Bl1, C0);
        C0 = MFMA(Al[0][0], Bh0, C0); C0 = MFMA(Al[0][1], Bh1, C0);
        C1 = MFMA(Ah[1][0], Bh0, C1); C1 = MFMA(Ah[1][1], Bh1, C1);
        C1 = MFMA(Ah[1][0], Bl0, C1); C1 = MFMA(Ah[1][1], Bl1, C1);
        C1 = MFMA(Al[1][0], Bh0, C1); C1 = MFMA(Al[1][1], Bh1, C1);

        const int code = cbase + col;
#pragma unroll
        for (int r = 0; r < 4; ++r) {
            {
                float c = C0[r];
                m2[r] = fminf(m2[r], fmaxf(m1[r], c));
                bool lt = c < m1[r];
                i1[r] = lt ? code : i1[r];
                m1[r] = fminf(m1[r], c);
            }
            {
                float c = C1[r];
                m2[4 + r] = fminf(m2[4 + r], fmaxf(m1[4 + r], c));
                bool lt = c < m1[4 + r];
                i1[4 + r] = lt ? code : i1[4 + r];
                m1[4 + r] = fminf(m1[4 + r], c);
            }
        }
    }

#pragma unroll
    for (int s = 0; s < 8; ++s) {
#pragma unroll
        for (int msk = 1; msk <= 8; msk <<= 1) {
            float om1 = __shfl_xor(m1[s], msk, 64);
            int   oi1 = __shfl_xor(i1[s], msk, 64);
            float om2 = __shfl_xor(m2[s], msk, 64);
            float nm2 = fminf(fmaxf(m1[s], om1), fminf(m2[s], om2));
            bool  take = om1 < m1[s];
            m1[s] = take ? om1 : m1[s];
            i1[s] = take ? oi1 : i1[s];
            m2[s] = nm2;
        }
    }

    if (col == 0) {
        const size_t hb = (size_t)half * N_TOK;
#pragma unroll
        for (int s = 0; s < 8; ++s) {
            int tl = (s >> 2) * 16 + quad * 4 + (s & 3);
            size_t off = hb + (size_t)(tokWave + tl);
            m1s[off] = m1[s];
            m2s[off] = m2[s];
            i1s[off] = i1[s];
        }
    }
}
#undef MFMA

// ---------------------------------------------------------------------------
// Epilogue. Phase A (1 thread/token): exact merge of the two halves
// (strict-<, half-0 priority on ties == ascending-scan first-min semantics;
// 2nd-best of union = min(m2a, m2b, max(m1a, m1b))), rescue flag, counts,
// idx write, rlist append. Phase B (16 lanes/token): fully-coalesced
// gather+write+SSE (64 lanes = 4 consecutive tokens = 1 KB contiguous).
// ---------------------------------------------------------------------------
__global__ __launch_bounds__(256, 8)
void vq_epi(const float* __restrict__ x,
            const float* __restrict__ w,
            const float* __restrict__ m1s,
            const float* __restrict__ m2s,
            const int* __restrict__ i1s,
            float* __restrict__ out,
            unsigned* __restrict__ counts,
            float* __restrict__ sse,
            int* __restrict__ rlist,
            unsigned* __restrict__ rcnt) {
    __shared__ int smw[256];
    const int t = blockIdx.x * 256 + threadIdx.x;

    // Phase A: merge halves
    float m1a = m1s[t],        m2a = m2s[t];
    float m1b = m1s[N_TOK + t], m2b = m2s[N_TOK + t];
    int   ia  = i1s[t],        ib  = i1s[N_TOK + t];
    bool  takeB = m1b < m1a;            // strict <: half0 (lower codes) wins ties
    float m1 = takeB ? m1b : m1a;
    int   wi = takeB ? ib : ia;
    float m2 = fminf(fminf(m2a, m2b), fmaxf(m1a, m1b));
    bool  resc = (m2 <= m1 + W_WINDOW);
    if (resc) {
        unsigned u = atomicAdd(rcnt, 1u);
        rlist[u] = t;
    } else {
        atomicAdd(&counts[wi], 1u);
    }
    out[OUT_IDX + t] = (float)wi;       // rescue overwrites flagged tokens later
    smw[threadIdx.x] = resc ? -1 : wi;
    __syncthreads();

    // Phase B: coalesced copy + SSE
    const int lane = threadIdx.x & 63;
    const int wv   = threadIdx.x >> 6;
    const int sub  = lane >> 4;         // token within 4-token pass
    const int i    = lane & 15;         // float4 index within 64-float row
    float err = 0.f;
#pragma unroll
    for (int p = 0; p < 16; ++p) {
        const int tl  = wv * 64 + p * 4 + sub;           // local token 0..255
        const int tok = blockIdx.x * 256 + tl;
        const int wi2 = smw[tl];
        if (wi2 >= 0) {
            float4 q  = ((const float4*)(w + (size_t)wi2 * D))[i];
            float4 xv = ((const float4*)(x + (size_t)tok * D))[i];
            float e0 = q.x - xv.x, e1 = q.y - xv.y;
            float e2 = q.z - xv.z, e3 = q.w - xv.w;
            err = fmaf(e0, e0, err);
            err = fmaf(e1, e1, err);
            err = fmaf(e2, e2, err);
            err = fmaf(e3, e3, err);
            ((float4*)(out + (size_t)tok * D))[i] = q;
        }
    }
#pragma unroll
    for (int o = 32; o > 0; o >>= 1) err += __shfl_down(err, o, 64);
    if (lane == 0) atomicAdd(sse, err);
}

// ---------------------------------------------------------------------------
// Rescue v2 (round-5-verified structure on the compacted list).
// Block = 1024 threads = 16 waves = 64 tokens (lane = token); wave wv scans
// codes [wv*64, wv*64+64) with the np-exact fp32 chain, wave-uniform scalar
// w loads. LDS first-min combine in ascending chunk order == np.argmin.
// ---------------------------------------------------------------------------
#define XR(d) ((d) < 16 ? xa[(d) & 15] : (d) < 32 ? xb[(d) & 15] \
              : (d) < 48 ? xc[(d) & 15] : xd[(d) & 15])

__global__ __launch_bounds__(1024, 1)
void vq_rescue(const float* __restrict__ x,
               const float* __restrict__ w,
               const float* __restrict__ enorm,
               float* __restrict__ out,
               unsigned* __restrict__ counts,
               float* __restrict__ sse,
               const int* __restrict__ rlist,
               const unsigned* __restrict__ rcnt) {
    const int lane = threadIdx.x & 63;
    const int wv   = __builtin_amdgcn_readfirstlane(threadIdx.x >> 6);  // 0..15
    const unsigned n = *rcnt;

    __shared__ float sd[16][64];
    __shared__ int   si[16][64];

    for (unsigned g = blockIdx.x; g * 64u < n; g += 256u) {
        const unsigned slot = g * 64u + (unsigned)lane;
        const bool valid = slot < n;
        const int t = valid ? rlist[slot] : 0;

        // Token row in 4 SSA vectors.
        const vf16* xp = (const vf16*)(x + (size_t)t * D);
        vf16 xa = xp[0], xb = xp[1], xc = xp[2], xd = xp[3];

        // Sx np-exact (8 accumulators, ascending blocks, pairwise tail).
        float Sx;
        {
            float r0, r1, r2, r3, r4, r5, r6, r7;
#define SQ(n) __fmul_rn(XR(n), XR(n))
            r0 = SQ(0); r1 = SQ(1); r2 = SQ(2); r3 = SQ(3);
            r4 = SQ(4); r5 = SQ(5); r6 = SQ(6); r7 = SQ(7);
#define ACC8(i)                                                           \
            r0 = __fadd_rn(r0, SQ(8*(i)+0)); r1 = __fadd_rn(r1, SQ(8*(i)+1)); \
            r2 = __fadd_rn(r2, SQ(8*(i)+2)); r3 = __fadd_rn(r3, SQ(8*(i)+3)); \
            r4 = __fadd_rn(r4, SQ(8*(i)+4)); r5 = __fadd_rn(r5, SQ(8*(i)+5)); \
            r6 = __fadd_rn(r6, SQ(8*(i)+6)); r7 = __fadd_rn(r7, SQ(8*(i)+7));
            ACC8(1) ACC8(2) ACC8(3) ACC8(4) ACC8(5) ACC8(6) ACC8(7)
            Sx = __fadd_rn(
                __fadd_rn(__fadd_rn(r0, r1), __fadd_rn(r2, r3)),
                __fadd_rn(__fadd_rn(r4, r5), __fadd_rn(r6, r7)));
#undef ACC8
#undef SQ
        }

        // np-exact scan of this wave's 64-code chunk (c ascending).
        float best = INFINITY;
        int   bidx = 0x7fffffff;
        const int c0 = wv * 64;
        for (int cc = 0; cc < 64; ++cc) {
            const int c = c0 + cc;
            const float* __restrict__ wr = w + (size_t)c * D;  // wave-uniform
            float a = 0.f;
#pragma unroll
            for (int d = 0; d < D; ++d) a = __fmaf_rn(wr[d], XR(d), a);
            float dist = __fsub_rn(__fadd_rn(Sx, enorm[c]), __fmul_rn(2.0f, a));
            bool lt = dist < best;  // strict <: first-min within chunk
            best = lt ? dist : best;
            bidx = lt ? c : bidx;
        }
        sd[wv][lane] = best;
        si[wv][lane] = bidx;
        __syncthreads();

        if (wv == 0) {
            float b  = sd[0][lane];
            int   bi = si[0][lane];
#pragma unroll
            for (int j = 1; j < 16; ++j) {
                float dj = sd[j][lane];
                bool  l  = dj < b;  // strict <: lower chunk (lower idx) wins ties
                b  = l ? dj : b;
                bi = l ? si[j][lane] : bi;
            }

            float err = 0.f;
            if (valid) {
                const float4* qr = (const float4*)(w + (size_t)bi * D);
                float4*       oq = (float4*)(out + (size_t)t * D);
#pragma unroll
                for (int i = 0; i < 16; ++i) {
                    float4 q = qr[i];
                    float e0 = q.x - XR(4 * i + 0);
                    float e1 = q.y - XR(4 * i + 1);
                    float e2 = q.z - XR(4 * i + 2);
                    float e3 = q.w - XR(4 * i + 3);
                    err = fmaf(e0, e0, err);
                    err = fmaf(e1, e1, err);
                    err = fmaf(e2, e2, err);
                    err = fmaf(e3, e3, err);
                    oq[i] = q;
                }
                out[OUT_IDX + t] = (float)bi;
                atomicAdd(&counts[bi], 1u);
            }
#pragma unroll
            for (int o = 32; o > 0; o >>= 1) err += __shfl_down(err, o, 64);
            if (lane == 0) atomicAdd(sse, err);
        }
        __syncthreads();
    }
}
#undef XR

// ---------------------------------------------------------------------------
__global__ void vq_fin(const unsigned* __restrict__ counts,
                       const float* __restrict__ sse,
                       float* __restrict__ out) {
    __shared__ float red[256];
    float s = 0.f;
    for (int k = threadIdx.x; k < K; k += 256) {
        float p = (float)counts[k] * (1.0f / (float)N_TOK);
        s += p * logf(p + 1e-10f);
    }
    red[threadIdx.x] = s;
    __syncthreads();
    for (int st = 128; st > 0; st >>= 1) {
        if (threadIdx.x < st) red[threadIdx.x] += red[threadIdx.x + st];
        __syncthreads();
    }
    if (threadIdx.x == 0) {
        out[OUT_PERP] = expf(-red[0]);
        out[OUT_LOSS] = 1.25f * (*sse) * (1.0f / 8388608.0f);  // (1+0.25)*MSE
    }
}

// ---------------------------------------------------------------------------
extern "C" void kernel_launch(void* const* d_in, const int* in_sizes, int n_in,
                              void* d_out, int out_size, void* d_ws, size_t ws_size,
                              hipStream_t stream) {
    const float* x = (const float*)d_in[0];  // [32,64,64,64] fp32
    const float* w = (const float*)d_in[1];  // [1024,64] fp32
    float* out = (float*)d_out;

    char* ws = (char*)d_ws;
    unsigned* counts = (unsigned*)(ws + 0);
    float*    enorm  = (float*)(ws + 4096);
    float*    sinit  = (float*)(ws + 8192);
    float*    sse    = (float*)(ws + 12288);
    unsigned* rcnt   = (unsigned*)(ws + 12292);
    short*    w_hi   = (short*)(ws + 16384);
    short*    w_lo   = (short*)(ws + 147456);
    float*    m1s    = (float*)(ws + 278528);
    float*    m2s    = (float*)(ws + 1327104);
    int*      i1s    = (int*)(ws + 2375680);
    int*      rlist  = (int*)(ws + 3424256);

    vq_prep<<<4, 256, 0, stream>>>(w, enorm, sinit, w_hi, w_lo, counts, sse, rcnt);
    vq_screen<<<dim3(N_TOK / 128, 2), 256, 0, stream>>>(x, sinit, w_hi, w_lo,
                                                        m1s, m2s, i1s);
    vq_epi<<<N_TOK / 256, 256, 0, stream>>>(x, w, m1s, m2s, i1s, out, counts,
                                            sse, rlist, rcnt);
    vq_rescue<<<256, 1024, 0, stream>>>(x, w, enorm, out, counts, sse, rlist, rcnt);
    vq_fin<<<1, 256, 0, stream>>>(counts, sse, out);
}

// Round 2
// 349.634 us; speedup vs baseline: 1.4954x; 1.4954x over previous
//
#include <hip/hip_runtime.h>
#include <math.h>

// Problem constants
#define N_TOK 131072   // 32*64*64 tokens
#define D     64       // embedding dim
#define K     1024     // codebook size

// Output layout (floats, concatenated in reference return order):
#define OUT_LOSS  8388608
#define OUT_IDX   8388609
#define OUT_PERP  8519681

// ws layout (bytes):
//   0        counts  u32[1024]
//   4096     enorm   f32[1024]  np-exact ||e||^2
//   8192     sinit   f32[1024]  fp64-accurate ||e||^2 (screen C-init)
//   12288    sse     f32
//   12292    rcnt    u32        rescue-list counter
//   16384    w_hi    s16[65536] bf16 hi split of w (128 KB)
//   147456   w_lo    s16[65536] bf16 lo split of w (128 KB)
//   278528   m1s     f32[2][131072] per-half best dist      (1 MB)
//   1327104  m2s     f32[2][131072] per-half 2nd-best dist  (1 MB)
//   2375680  i1s     i32[2][131072] per-half best index     (1 MB)
//   3424256  rlist   i32[131072] compacted rescue token ids (512 KB)

#define W_WINDOW 1e-4f

typedef short bf16x8 __attribute__((ext_vector_type(8)));
typedef float f32x4  __attribute__((ext_vector_type(4)));
typedef float vf16   __attribute__((ext_vector_type(16)));

// ---------------------------------------------------------------------------
__device__ __forceinline__ float np_pairsum64(const float* sq) {
    float r[8];
#pragma unroll
    for (int j = 0; j < 8; ++j) r[j] = sq[j];
#pragma unroll
    for (int i = 8; i < 64; i += 8) {
#pragma unroll
        for (int j = 0; j < 8; ++j) r[j] = __fadd_rn(r[j], sq[i + j]);
    }
    return __fadd_rn(
        __fadd_rn(__fadd_rn(r[0], r[1]), __fadd_rn(r[2], r[3])),
        __fadd_rn(__fadd_rn(r[4], r[5]), __fadd_rn(r[6], r[7])));
}

__device__ __forceinline__ short bf16_trunc(float f) {
    return (short)(__float_as_uint(f) >> 16);
}
__device__ __forceinline__ float bf16_up(short s) {
    return __uint_as_float(((unsigned)(unsigned short)s) << 16);
}

// ---------------------------------------------------------------------------
__global__ void vq_prep(const float* __restrict__ w,
                        float* __restrict__ enorm,
                        float* __restrict__ sinit,
                        short* __restrict__ w_hi,
                        short* __restrict__ w_lo,
                        unsigned* __restrict__ counts,
                        float* __restrict__ sse,
                        unsigned* __restrict__ rcnt) {
    int k = blockIdx.x * blockDim.x + threadIdx.x;
    if (k < K) {
        const float* wr = w + (size_t)k * D;
        float sq[D];
        double acc = 0.0;
#pragma unroll
        for (int i = 0; i < D; ++i) {
            float v = wr[i];
            sq[i] = __fmul_rn(v, v);
            acc += (double)v * (double)v;
            short hi = bf16_trunc(v);
            float res = v - bf16_up(hi);
            short lo = bf16_trunc(res);
            w_hi[(size_t)k * D + i] = hi;
            w_lo[(size_t)k * D + i] = lo;
        }
        enorm[k] = np_pairsum64(sq);
        sinit[k] = (float)acc;
        counts[k] = 0u;
    }
    if (k == 0) { *sse = 0.f; *rcnt = 0u; }
}

// ---------------------------------------------------------------------------
// Screen, split-K: blockIdx.y = half selects code tiles [half*32, half*32+32).
// Per-half math is identical (ascending tiles, strict-< first-min); the exact
// merge happens in vq_epi. 2x grid (2048 blocks) -> 8 blocks/CU residency.
// launch_bounds STAYS at min-waves=4: the natural 48-VGPR allocation already
// permits 32 waves/CU (<=64 VGPR rule); forcing 8 clamps to 32 VGPR and
// spills ~570 MB of scratch to HBM (round-1 regression).
// ---------------------------------------------------------------------------
#define MFMA(A, B, C) __builtin_amdgcn_mfma_f32_16x16x32_bf16(A, B, C, 0, 0, 0)

__global__ __launch_bounds__(256, 4)
void vq_screen(const float* __restrict__ x,
               const float* __restrict__ sinit,
               const short* __restrict__ w_hi,
               const short* __restrict__ w_lo,
               float* __restrict__ m1s,
               float* __restrict__ m2s,
               int* __restrict__ i1s) {
    const int lane = threadIdx.x & 63;
    const int wv   = __builtin_amdgcn_readfirstlane(threadIdx.x >> 6);
    const int quad = lane >> 4;
    const int col  = lane & 15;
    const int tokWave = blockIdx.x * 128 + wv * 32;
    const int half = blockIdx.y;           // 0: codes 0..511, 1: codes 512..1023
    const int t0 = half * 32;

    bf16x8 Ah[2][2], Al[2][2];
#pragma unroll
    for (int mt = 0; mt < 2; ++mt) {
#pragma unroll
        for (int ks = 0; ks < 2; ++ks) {
            const float4* ap = (const float4*)(x + (size_t)(tokWave + mt * 16 + col) * D
                                               + ks * 32 + quad * 8);
            float4 u0 = ap[0], u1 = ap[1];
            float f[8] = {u0.x, u0.y, u0.z, u0.w, u1.x, u1.y, u1.z, u1.w};
            bf16x8 h, l;
#pragma unroll
            for (int j = 0; j < 8; ++j) {
                float v = -2.0f * f[j];
                short hi = bf16_trunc(v);
                float res = v - bf16_up(hi);
                h[j] = hi;
                l[j] = bf16_trunc(res);
            }
            Ah[mt][ks] = h;
            Al[mt][ks] = l;
        }
    }

    float m1[8], m2[8];
    int   i1[8];
#pragma unroll
    for (int s = 0; s < 8; ++s) { m1[s] = INFINITY; m2[s] = INFINITY; i1[s] = 0; }

    for (int tile = t0; tile < t0 + 32; ++tile) {
        const int cbase = tile * 16;
        const size_t rowoff = (size_t)(cbase + col) * D;
        bf16x8 Bh0 = *(const bf16x8*)(w_hi + rowoff + 0 * 32 + quad * 8);
        bf16x8 Bh1 = *(const bf16x8*)(w_hi + rowoff + 1 * 32 + quad * 8);
        bf16x8 Bl0 = *(const bf16x8*)(w_lo + rowoff + 0 * 32 + quad * 8);
        bf16x8 Bl1 = *(const bf16x8*)(w_lo + rowoff + 1 * 32 + quad * 8);
        float si = sinit[cbase + col];
        f32x4 C0 = {si, si, si, si};
        f32x4 C1 = {si, si, si, si};
        C0 = MFMA(Ah[0][0], Bh0, C0); C0 = MFMA(Ah[0][1], Bh1, C0);
        C0 = MFMA(Ah[0][0], Bl0, C0); C0 = MFMA(Ah[0][1], Bl1, C0);
        C0 = MFMA(Al[0][0], Bh0, C0); C0 = MFMA(Al[0][1], Bh1, C0);
        C1 = MFMA(Ah[1][0], Bh0, C1); C1 = MFMA(Ah[1][1], Bh1, C1);
        C1 = MFMA(Ah[1][0], Bl0, C1); C1 = MFMA(Ah[1][1], Bl1, C1);
        C1 = MFMA(Al[1][0], Bh0, C1); C1 = MFMA(Al[1][1], Bh1, C1);

        const int code = cbase + col;
#pragma unroll
        for (int r = 0; r < 4; ++r) {
            {
                float c = C0[r];
                m2[r] = fminf(m2[r], fmaxf(m1[r], c));
                bool lt = c < m1[r];
                i1[r] = lt ? code : i1[r];
                m1[r] = fminf(m1[r], c);
            }
            {
                float c = C1[r];
                m2[4 + r] = fminf(m2[4 + r], fmaxf(m1[4 + r], c));
                bool lt = c < m1[4 + r];
                i1[4 + r] = lt ? code : i1[4 + r];
                m1[4 + r] = fminf(m1[4 + r], c);
            }
        }
    }

#pragma unroll
    for (int s = 0; s < 8; ++s) {
#pragma unroll
        for (int msk = 1; msk <= 8; msk <<= 1) {
            float om1 = __shfl_xor(m1[s], msk, 64);
            int   oi1 = __shfl_xor(i1[s], msk, 64);
            float om2 = __shfl_xor(m2[s], msk, 64);
            float nm2 = fminf(fmaxf(m1[s], om1), fminf(m2[s], om2));
            bool  take = om1 < m1[s];
            m1[s] = take ? om1 : m1[s];
            i1[s] = take ? oi1 : i1[s];
            m2[s] = nm2;
        }
    }

    if (col == 0) {
        const size_t hb = (size_t)half * N_TOK;
#pragma unroll
        for (int s = 0; s < 8; ++s) {
            int tl = (s >> 2) * 16 + quad * 4 + (s & 3);
            size_t off = hb + (size_t)(tokWave + tl);
            m1s[off] = m1[s];
            m2s[off] = m2[s];
            i1s[off] = i1[s];
        }
    }
}
#undef MFMA

// ---------------------------------------------------------------------------
// Epilogue. Phase A (1 thread/token): exact merge of the two halves
// (strict-<, half-0 priority on ties == ascending-scan first-min semantics;
// 2nd-best of union = min(m2a, m2b, max(m1a, m1b))), rescue flag, counts,
// idx write, rlist append. Phase B (16 lanes/token): fully-coalesced
// gather+write+SSE (64 lanes = 4 consecutive tokens = 1 KB contiguous).
// ---------------------------------------------------------------------------
__global__ __launch_bounds__(256, 4)
void vq_epi(const float* __restrict__ x,
            const float* __restrict__ w,
            const float* __restrict__ m1s,
            const float* __restrict__ m2s,
            const int* __restrict__ i1s,
            float* __restrict__ out,
            unsigned* __restrict__ counts,
            float* __restrict__ sse,
            int* __restrict__ rlist,
            unsigned* __restrict__ rcnt) {
    __shared__ int smw[256];
    const int t = blockIdx.x * 256 + threadIdx.x;

    // Phase A: merge halves
    float m1a = m1s[t],        m2a = m2s[t];
    float m1b = m1s[N_TOK + t], m2b = m2s[N_TOK + t];
    int   ia  = i1s[t],        ib  = i1s[N_TOK + t];
    bool  takeB = m1b < m1a;            // strict <: half0 (lower codes) wins ties
    float m1 = takeB ? m1b : m1a;
    int   wi = takeB ? ib : ia;
    float m2 = fminf(fminf(m2a, m2b), fmaxf(m1a, m1b));
    bool  resc = (m2 <= m1 + W_WINDOW);
    if (resc) {
        unsigned u = atomicAdd(rcnt, 1u);
        rlist[u] = t;
    } else {
        atomicAdd(&counts[wi], 1u);
    }
    out[OUT_IDX + t] = (float)wi;       // rescue overwrites flagged tokens later
    smw[threadIdx.x] = resc ? -1 : wi;
    __syncthreads();

    // Phase B: coalesced copy + SSE
    const int lane = threadIdx.x & 63;
    const int wv   = threadIdx.x >> 6;
    const int sub  = lane >> 4;         // token within 4-token pass
    const int i    = lane & 15;         // float4 index within 64-float row
    float err = 0.f;
#pragma unroll
    for (int p = 0; p < 16; ++p) {
        const int tl  = wv * 64 + p * 4 + sub;           // local token 0..255
        const int tok = blockIdx.x * 256 + tl;
        const int wi2 = smw[tl];
        if (wi2 >= 0) {
            float4 q  = ((const float4*)(w + (size_t)wi2 * D))[i];
            float4 xv = ((const float4*)(x + (size_t)tok * D))[i];
            float e0 = q.x - xv.x, e1 = q.y - xv.y;
            float e2 = q.z - xv.z, e3 = q.w - xv.w;
            err = fmaf(e0, e0, err);
            err = fmaf(e1, e1, err);
            err = fmaf(e2, e2, err);
            err = fmaf(e3, e3, err);
            ((float4*)(out + (size_t)tok * D))[i] = q;
        }
    }
#pragma unroll
    for (int o = 32; o > 0; o >>= 1) err += __shfl_down(err, o, 64);
    if (lane == 0) atomicAdd(sse, err);
}

// ---------------------------------------------------------------------------
// Rescue v2 (round-5-verified structure on the compacted list).
// Block = 1024 threads = 16 waves = 64 tokens (lane = token); wave wv scans
// codes [wv*64, wv*64+64) with the np-exact fp32 chain, wave-uniform scalar
// w loads. LDS first-min combine in ascending chunk order == np.argmin.
// ---------------------------------------------------------------------------
#define XR(d) ((d) < 16 ? xa[(d) & 15] : (d) < 32 ? xb[(d) & 15] \
              : (d) < 48 ? xc[(d) & 15] : xd[(d) & 15])

__global__ __launch_bounds__(1024, 1)
void vq_rescue(const float* __restrict__ x,
               const float* __restrict__ w,
               const float* __restrict__ enorm,
               float* __restrict__ out,
               unsigned* __restrict__ counts,
               float* __restrict__ sse,
               const int* __restrict__ rlist,
               const unsigned* __restrict__ rcnt) {
    const int lane = threadIdx.x & 63;
    const int wv   = __builtin_amdgcn_readfirstlane(threadIdx.x >> 6);  // 0..15
    const unsigned n = *rcnt;

    __shared__ float sd[16][64];
    __shared__ int   si[16][64];

    for (unsigned g = blockIdx.x; g * 64u < n; g += 256u) {
        const unsigned slot = g * 64u + (unsigned)lane;
        const bool valid = slot < n;
        const int t = valid ? rlist[slot] : 0;

        // Token row in 4 SSA vectors.
        const vf16* xp = (const vf16*)(x + (size_t)t * D);
        vf16 xa = xp[0], xb = xp[1], xc = xp[2], xd = xp[3];

        // Sx np-exact (8 accumulators, ascending blocks, pairwise tail).
        float Sx;
        {
            float r0, r1, r2, r3, r4, r5, r6, r7;
#define SQ(n) __fmul_rn(XR(n), XR(n))
            r0 = SQ(0); r1 = SQ(1); r2 = SQ(2); r3 = SQ(3);
            r4 = SQ(4); r5 = SQ(5); r6 = SQ(6); r7 = SQ(7);
#define ACC8(i)                                                           \
            r0 = __fadd_rn(r0, SQ(8*(i)+0)); r1 = __fadd_rn(r1, SQ(8*(i)+1)); \
            r2 = __fadd_rn(r2, SQ(8*(i)+2)); r3 = __fadd_rn(r3, SQ(8*(i)+3)); \
            r4 = __fadd_rn(r4, SQ(8*(i)+4)); r5 = __fadd_rn(r5, SQ(8*(i)+5)); \
            r6 = __fadd_rn(r6, SQ(8*(i)+6)); r7 = __fadd_rn(r7, SQ(8*(i)+7));
            ACC8(1) ACC8(2) ACC8(3) ACC8(4) ACC8(5) ACC8(6) ACC8(7)
            Sx = __fadd_rn(
                __fadd_rn(__fadd_rn(r0, r1), __fadd_rn(r2, r3)),
                __fadd_rn(__fadd_rn(r4, r5), __fadd_rn(r6, r7)));
#undef ACC8
#undef SQ
        }

        // np-exact scan of this wave's 64-code chunk (c ascending).
        float best = INFINITY;
        int   bidx = 0x7fffffff;
        const int c0 = wv * 64;
        for (int cc = 0; cc < 64; ++cc) {
            const int c = c0 + cc;
            const float* __restrict__ wr = w + (size_t)c * D;  // wave-uniform
            float a = 0.f;
#pragma unroll
            for (int d = 0; d < D; ++d) a = __fmaf_rn(wr[d], XR(d), a);
            float dist = __fsub_rn(__fadd_rn(Sx, enorm[c]), __fmul_rn(2.0f, a));
            bool lt = dist < best;  // strict <: first-min within chunk
            best = lt ? dist : best;
            bidx = lt ? c : bidx;
        }
        sd[wv][lane] = best;
        si[wv][lane] = bidx;
        __syncthreads();

        if (wv == 0) {
            float b  = sd[0][lane];
            int   bi = si[0][lane];
#pragma unroll
            for (int j = 1; j < 16; ++j) {
                float dj = sd[j][lane];
                bool  l  = dj < b;  // strict <: lower chunk (lower idx) wins ties
                b  = l ? dj : b;
                bi = l ? si[j][lane] : bi;
            }

            float err = 0.f;
            if (valid) {
                const float4* qr = (const float4*)(w + (size_t)bi * D);
                float4*       oq = (float4*)(out + (size_t)t * D);
#pragma unroll
                for (int i = 0; i < 16; ++i) {
                    float4 q = qr[i];
                    float e0 = q.x - XR(4 * i + 0);
                    float e1 = q.y - XR(4 * i + 1);
                    float e2 = q.z - XR(4 * i + 2);
                    float e3 = q.w - XR(4 * i + 3);
                    err = fmaf(e0, e0, err);
                    err = fmaf(e1, e1, err);
                    err = fmaf(e2, e2, err);
                    err = fmaf(e3, e3, err);
                    oq[i] = q;
                }
                out[OUT_IDX + t] = (float)bi;
                atomicAdd(&counts[bi], 1u);
            }
#pragma unroll
            for (int o = 32; o > 0; o >>= 1) err += __shfl_down(err, o, 64);
            if (lane == 0) atomicAdd(sse, err);
        }
        __syncthreads();
    }
}
#undef XR

// ---------------------------------------------------------------------------
__global__ void vq_fin(const unsigned* __restrict__ counts,
                       const float* __restrict__ sse,
                       float* __restrict__ out) {
    __shared__ float red[256];
    float s = 0.f;
    for (int k = threadIdx.x; k < K; k += 256) {
        float p = (float)counts[k] * (1.0f / (float)N_TOK);
        s += p * logf(p + 1e-10f);
    }
    red[threadIdx.x] = s;
    __syncthreads();
    for (int st = 128; st > 0; st >>= 1) {
        if (threadIdx.x < st) red[threadIdx.x] += red[threadIdx.x + st];
        __syncthreads();
    }
    if (threadIdx.x == 0) {
        out[OUT_PERP] = expf(-red[0]);
        out[OUT_LOSS] = 1.25f * (*sse) * (1.0f / 8388608.0f);  // (1+0.25)*MSE
    }
}

// ---------------------------------------------------------------------------
extern "C" void kernel_launch(void* const* d_in, const int* in_sizes, int n_in,
                              void* d_out, int out_size, void* d_ws, size_t ws_size,
                              hipStream_t stream) {
    const float* x = (const float*)d_in[0];  // [32,64,64,64] fp32
    const float* w = (const float*)d_in[1];  // [1024,64] fp32
    float* out = (float*)d_out;

    char* ws = (char*)d_ws;
    unsigned* counts = (unsigned*)(ws + 0);
    float*    enorm  = (float*)(ws + 4096);
    float*    sinit  = (float*)(ws + 8192);
    float*    sse    = (float*)(ws + 12288);
    unsigned* rcnt   = (unsigned*)(ws + 12292);
    short*    w_hi   = (short*)(ws + 16384);
    short*    w_lo   = (short*)(ws + 147456);
    float*    m1s    = (float*)(ws + 278528);
    float*    m2s    = (float*)(ws + 1327104);
    int*      i1s    = (int*)(ws + 2375680);
    int*      rlist  = (int*)(ws + 3424256);

    vq_prep<<<4, 256, 0, stream>>>(w, enorm, sinit, w_hi, w_lo, counts, sse, rcnt);
    vq_screen<<<dim3(N_TOK / 128, 2), 256, 0, stream>>>(x, sinit, w_hi, w_lo,
                                                        m1s, m2s, i1s);
    vq_epi<<<N_TOK / 256, 256, 0, stream>>>(x, w, m1s, m2s, i1s, out, counts,
                                            sse, rlist, rcnt);
    vq_rescue<<<256, 1024, 0, stream>>>(x, w, enorm, out, counts, sse, rlist, rcnt);
    vq_fin<<<1, 256, 0, stream>>>(counts, sse, out);
}

// Round 3
// 324.216 us; speedup vs baseline: 1.6126x; 1.0784x over previous
//
#include <hip/hip_runtime.h>
#include <math.h>

// Problem constants
#define N_TOK 131072   // 32*64*64 tokens
#define D     64       // embedding dim
#define K     1024     // codebook size

// Output layout (floats, concatenated in reference return order):
#define OUT_LOSS  8388608
#define OUT_IDX   8388609
#define OUT_PERP  8519681

// ws layout (bytes):
//   0        counts  u32[1024]
//   4096     enorm   f32[1024]  np-exact ||e||^2
//   8192     sinit   f32[1024]  fp64-accurate ||e||^2 (screen C-init)
//   12288    sse     f32
//   12292    rcnt    u32        rescue-list counter
//   16384    w_hi    s16[65536] bf16 hi split of w (128 KB)
//   147456   w_lo    s16[65536] bf16 lo split of w (128 KB)
//   278528   win     i32[131072] packed winner (bit31 = needs rescue)
//   802816   rlist   i32[131072] compacted rescue token ids

#define W_WINDOW 1e-4f

typedef short bf16x8 __attribute__((ext_vector_type(8)));
typedef float f32x4  __attribute__((ext_vector_type(4)));
typedef float vf16   __attribute__((ext_vector_type(16)));

// ---------------------------------------------------------------------------
__device__ __forceinline__ float np_pairsum64(const float* sq) {
    float r[8];
#pragma unroll
    for (int j = 0; j < 8; ++j) r[j] = sq[j];
#pragma unroll
    for (int i = 8; i < 64; i += 8) {
#pragma unroll
        for (int j = 0; j < 8; ++j) r[j] = __fadd_rn(r[j], sq[i + j]);
    }
    return __fadd_rn(
        __fadd_rn(__fadd_rn(r[0], r[1]), __fadd_rn(r[2], r[3])),
        __fadd_rn(__fadd_rn(r[4], r[5]), __fadd_rn(r[6], r[7])));
}

__device__ __forceinline__ short bf16_trunc(float f) {
    return (short)(__float_as_uint(f) >> 16);
}
__device__ __forceinline__ float bf16_up(short s) {
    return __uint_as_float(((unsigned)(unsigned short)s) << 16);
}

// ---------------------------------------------------------------------------
__global__ void vq_prep(const float* __restrict__ w,
                        float* __restrict__ enorm,
                        float* __restrict__ sinit,
                        short* __restrict__ w_hi,
                        short* __restrict__ w_lo,
                        unsigned* __restrict__ counts,
                        float* __restrict__ sse,
                        unsigned* __restrict__ rcnt) {
    int k = blockIdx.x * blockDim.x + threadIdx.x;
    if (k < K) {
        const float* wr = w + (size_t)k * D;
        float sq[D];
        double acc = 0.0;
#pragma unroll
        for (int i = 0; i < D; ++i) {
            float v = wr[i];
            sq[i] = __fmul_rn(v, v);
            acc += (double)v * (double)v;
            short hi = bf16_trunc(v);
            float res = v - bf16_up(hi);
            short lo = bf16_trunc(res);
            w_hi[(size_t)k * D + i] = hi;
            w_lo[(size_t)k * D + i] = lo;
        }
        enorm[k] = np_pairsum64(sq);
        sinit[k] = (float)acc;
        counts[k] = 0u;
    }
    if (k == 0) { *sse = 0.f; *rcnt = 0u; }
}

// ---------------------------------------------------------------------------
// Screen (round-0 math, bit-identical accumulation order) + depth-1 register
// software pipeline on the B tiles. Occupancy is register-pinned at 4
// waves/SIMD (unified VGPR+AGPR footprint ~110), so latency must be hidden
// with ILP: tile t+1's 4 B-loads + sinit issue before tile t's MFMA chain
// consumes the other buffer. Two NAMED buffers (P/Q), manual 2x unroll —
// no runtime-indexed register arrays (scratch trap).
// ---------------------------------------------------------------------------
#define MFMA(A, B, C) __builtin_amdgcn_mfma_f32_16x16x32_bf16(A, B, C, 0, 0, 0)

__device__ __forceinline__ void tile_step(
    int code, const bf16x8 (&Ah)[2][2], const bf16x8 (&Al)[2][2],
    bf16x8 H0, bf16x8 H1, bf16x8 L0, bf16x8 L1, float si,
    float (&m1)[8], float (&m2)[8], int (&i1)[8]) {
    f32x4 C0 = {si, si, si, si};
    f32x4 C1 = {si, si, si, si};
    C0 = MFMA(Ah[0][0], H0, C0); C0 = MFMA(Ah[0][1], H1, C0);
    C0 = MFMA(Ah[0][0], L0, C0); C0 = MFMA(Ah[0][1], L1, C0);
    C0 = MFMA(Al[0][0], H0, C0); C0 = MFMA(Al[0][1], H1, C0);
    C1 = MFMA(Ah[1][0], H0, C1); C1 = MFMA(Ah[1][1], H1, C1);
    C1 = MFMA(Ah[1][0], L0, C1); C1 = MFMA(Ah[1][1], L1, C1);
    C1 = MFMA(Al[1][0], H0, C1); C1 = MFMA(Al[1][1], H1, C1);
#pragma unroll
    for (int r = 0; r < 4; ++r) {
        {
            float c = C0[r];
            m2[r] = fminf(m2[r], fmaxf(m1[r], c));
            bool lt = c < m1[r];
            i1[r] = lt ? code : i1[r];
            m1[r] = fminf(m1[r], c);
        }
        {
            float c = C1[r];
            m2[4 + r] = fminf(m2[4 + r], fmaxf(m1[4 + r], c));
            bool lt = c < m1[4 + r];
            i1[4 + r] = lt ? code : i1[4 + r];
            m1[4 + r] = fminf(m1[4 + r], c);
        }
    }
}

__global__ __launch_bounds__(256, 4)
void vq_screen(const float* __restrict__ x,
               const float* __restrict__ sinit,
               const short* __restrict__ w_hi,
               const short* __restrict__ w_lo,
               int* __restrict__ win) {
    const int lane = threadIdx.x & 63;
    const int wv   = __builtin_amdgcn_readfirstlane(threadIdx.x >> 6);
    const int quad = lane >> 4;
    const int col  = lane & 15;
    const int tokWave = blockIdx.x * 128 + wv * 32;

    bf16x8 Ah[2][2], Al[2][2];
#pragma unroll
    for (int mt = 0; mt < 2; ++mt) {
#pragma unroll
        for (int ks = 0; ks < 2; ++ks) {
            const float4* ap = (const float4*)(x + (size_t)(tokWave + mt * 16 + col) * D
                                               + ks * 32 + quad * 8);
            float4 u0 = ap[0], u1 = ap[1];
            float f[8] = {u0.x, u0.y, u0.z, u0.w, u1.x, u1.y, u1.z, u1.w};
            bf16x8 h, l;
#pragma unroll
            for (int j = 0; j < 8; ++j) {
                float v = -2.0f * f[j];
                short hi = bf16_trunc(v);
                float res = v - bf16_up(hi);
                h[j] = hi;
                l[j] = bf16_trunc(res);
            }
            Ah[mt][ks] = h;
            Al[mt][ks] = l;
        }
    }

    float m1[8], m2[8];
    int   i1[8];
#pragma unroll
    for (int s = 0; s < 8; ++s) { m1[s] = INFINITY; m2[s] = INFINITY; i1[s] = 0; }

    // Per-lane B base: row (col) of the current 16-code tile, quad-sliced.
    const short* __restrict__ whp = w_hi + (size_t)col * D + quad * 8;
    const short* __restrict__ wlp = w_lo + (size_t)col * D + quad * 8;
    // tile stride in shorts: 16 rows * 64 = 1024

#define LOADB(tl, H0, H1, L0, L1, SI)                              \
    {                                                              \
        const size_t o_ = (size_t)(tl) * 1024;                     \
        H0 = *(const bf16x8*)(whp + o_);                           \
        H1 = *(const bf16x8*)(whp + o_ + 32);                      \
        L0 = *(const bf16x8*)(wlp + o_);                           \
        L1 = *(const bf16x8*)(wlp + o_ + 32);                      \
        SI = sinit[(tl) * 16 + col];                               \
    }

    bf16x8 PH0, PH1, PL0, PL1;
    bf16x8 QH0, QH1, QL0, QL1;
    float  Psi, Qsi;
    LOADB(0, PH0, PH1, PL0, PL1, Psi);

    for (int tile = 0; tile < 64; tile += 2) {
        LOADB(tile + 1, QH0, QH1, QL0, QL1, Qsi);
        tile_step(tile * 16 + col, Ah, Al, PH0, PH1, PL0, PL1, Psi, m1, m2, i1);
        const int tn = (tile + 2) & 63;   // last iter: harmless dummy reload of tile 0
        LOADB(tn, PH0, PH1, PL0, PL1, Psi);
        tile_step((tile + 1) * 16 + col, Ah, Al, QH0, QH1, QL0, QL1, Qsi, m1, m2, i1);
    }
#undef LOADB

#pragma unroll
    for (int s = 0; s < 8; ++s) {
#pragma unroll
        for (int msk = 1; msk <= 8; msk <<= 1) {
            float om1 = __shfl_xor(m1[s], msk, 64);
            int   oi1 = __shfl_xor(i1[s], msk, 64);
            float om2 = __shfl_xor(m2[s], msk, 64);
            float nm2 = fminf(fmaxf(m1[s], om1), fminf(m2[s], om2));
            bool  take = om1 < m1[s];
            m1[s] = take ? om1 : m1[s];
            i1[s] = take ? oi1 : i1[s];
            m2[s] = nm2;
        }
    }

    if (col == 0) {
#pragma unroll
        for (int s = 0; s < 8; ++s) {
            int tl = (s >> 2) * 16 + quad * 4 + (s & 3);
            bool resc = (m2[s] <= m1[s] + W_WINDOW);
            win[tokWave + tl] = resc ? (i1[s] | 0x80000000) : i1[s];
        }
    }
}
#undef MFMA

// ---------------------------------------------------------------------------
// Epilogue. Phase A (1 thread/token): unpack win[], rescue flag -> rlist,
// else counts+idx. Phase B (16 lanes/token): fully-coalesced gather+write+SSE
// (64 lanes = 4 consecutive tokens = 1 KB contiguous per wave instruction).
// ---------------------------------------------------------------------------
__global__ __launch_bounds__(256, 4)
void vq_epi(const float* __restrict__ x,
            const float* __restrict__ w,
            const int* __restrict__ win,
            float* __restrict__ out,
            unsigned* __restrict__ counts,
            float* __restrict__ sse,
            int* __restrict__ rlist,
            unsigned* __restrict__ rcnt) {
    __shared__ int smw[256];
    const int t = blockIdx.x * 256 + threadIdx.x;

    const int wi = win[t];
    if (wi < 0) {
        unsigned u = atomicAdd(rcnt, 1u);
        rlist[u] = t;
        smw[threadIdx.x] = -1;
    } else {
        atomicAdd(&counts[wi], 1u);
        out[OUT_IDX + t] = (float)wi;
        smw[threadIdx.x] = wi;
    }
    __syncthreads();

    // Phase B: coalesced copy + SSE
    const int lane = threadIdx.x & 63;
    const int wvi  = threadIdx.x >> 6;
    const int sub  = lane >> 4;         // token within 4-token pass
    const int i    = lane & 15;         // float4 index within 64-float row
    float err = 0.f;
#pragma unroll
    for (int p = 0; p < 16; ++p) {
        const int tl  = wvi * 64 + p * 4 + sub;          // local token 0..255
        const int tok = blockIdx.x * 256 + tl;
        const int wi2 = smw[tl];
        if (wi2 >= 0) {
            float4 q  = ((const float4*)(w + (size_t)wi2 * D))[i];
            float4 xv = ((const float4*)(x + (size_t)tok * D))[i];
            float e0 = q.x - xv.x, e1 = q.y - xv.y;
            float e2 = q.z - xv.z, e3 = q.w - xv.w;
            err = fmaf(e0, e0, err);
            err = fmaf(e1, e1, err);
            err = fmaf(e2, e2, err);
            err = fmaf(e3, e3, err);
            ((float4*)(out + (size_t)tok * D))[i] = q;
        }
    }
#pragma unroll
    for (int o = 32; o > 0; o >>= 1) err += __shfl_down(err, o, 64);
    if (lane == 0) atomicAdd(sse, err);
}

// ---------------------------------------------------------------------------
// Rescue v2 (round-5-verified structure on the compacted list).
// Block = 1024 threads = 16 waves = 64 tokens (lane = token); wave wv scans
// codes [wv*64, wv*64+64) with the np-exact fp32 chain, wave-uniform scalar
// w loads. LDS first-min combine in ascending chunk order == np.argmin.
// ---------------------------------------------------------------------------
#define XR(d) ((d) < 16 ? xa[(d) & 15] : (d) < 32 ? xb[(d) & 15] \
              : (d) < 48 ? xc[(d) & 15] : xd[(d) & 15])

__global__ __launch_bounds__(1024, 1)
void vq_rescue(const float* __restrict__ x,
               const float* __restrict__ w,
               const float* __restrict__ enorm,
               float* __restrict__ out,
               unsigned* __restrict__ counts,
               float* __restrict__ sse,
               const int* __restrict__ rlist,
               const unsigned* __restrict__ rcnt) {
    const int lane = threadIdx.x & 63;
    const int wv   = __builtin_amdgcn_readfirstlane(threadIdx.x >> 6);  // 0..15
    const unsigned n = *rcnt;

    __shared__ float sd[16][64];
    __shared__ int   si[16][64];

    for (unsigned g = blockIdx.x; g * 64u < n; g += 256u) {
        const unsigned slot = g * 64u + (unsigned)lane;
        const bool valid = slot < n;
        const int t = valid ? rlist[slot] : 0;

        // Token row in 4 SSA vectors.
        const vf16* xp = (const vf16*)(x + (size_t)t * D);
        vf16 xa = xp[0], xb = xp[1], xc = xp[2], xd = xp[3];

        // Sx np-exact (8 accumulators, ascending blocks, pairwise tail).
        float Sx;
        {
            float r0, r1, r2, r3, r4, r5, r6, r7;
#define SQ(n) __fmul_rn(XR(n), XR(n))
            r0 = SQ(0); r1 = SQ(1); r2 = SQ(2); r3 = SQ(3);
            r4 = SQ(4); r5 = SQ(5); r6 = SQ(6); r7 = SQ(7);
#define ACC8(i)                                                           \
            r0 = __fadd_rn(r0, SQ(8*(i)+0)); r1 = __fadd_rn(r1, SQ(8*(i)+1)); \
            r2 = __fadd_rn(r2, SQ(8*(i)+2)); r3 = __fadd_rn(r3, SQ(8*(i)+3)); \
            r4 = __fadd_rn(r4, SQ(8*(i)+4)); r5 = __fadd_rn(r5, SQ(8*(i)+5)); \
            r6 = __fadd_rn(r6, SQ(8*(i)+6)); r7 = __fadd_rn(r7, SQ(8*(i)+7));
            ACC8(1) ACC8(2) ACC8(3) ACC8(4) ACC8(5) ACC8(6) ACC8(7)
            Sx = __fadd_rn(
                __fadd_rn(__fadd_rn(r0, r1), __fadd_rn(r2, r3)),
                __fadd_rn(__fadd_rn(r4, r5), __fadd_rn(r6, r7)));
#undef ACC8
#undef SQ
        }

        // np-exact scan of this wave's 64-code chunk (c ascending).
        float best = INFINITY;
        int   bidx = 0x7fffffff;
        const int c0 = wv * 64;
        for (int cc = 0; cc < 64; ++cc) {
            const int c = c0 + cc;
            const float* __restrict__ wr = w + (size_t)c * D;  // wave-uniform
            float a = 0.f;
#pragma unroll
            for (int d = 0; d < D; ++d) a = __fmaf_rn(wr[d], XR(d), a);
            float dist = __fsub_rn(__fadd_rn(Sx, enorm[c]), __fmul_rn(2.0f, a));
            bool lt = dist < best;  // strict <: first-min within chunk
            best = lt ? dist : best;
            bidx = lt ? c : bidx;
        }
        sd[wv][lane] = best;
        si[wv][lane] = bidx;
        __syncthreads();

        if (wv == 0) {
            float b  = sd[0][lane];
            int   bi = si[0][lane];
#pragma unroll
            for (int j = 1; j < 16; ++j) {
                float dj = sd[j][lane];
                bool  l  = dj < b;  // strict <: lower chunk (lower idx) wins ties
                b  = l ? dj : b;
                bi = l ? si[j][lane] : bi;
            }

            float err = 0.f;
            if (valid) {
                const float4* qr = (const float4*)(w + (size_t)bi * D);
                float4*       oq = (float4*)(out + (size_t)t * D);
#pragma unroll
                for (int i = 0; i < 16; ++i) {
                    float4 q = qr[i];
                    float e0 = q.x - XR(4 * i + 0);
                    float e1 = q.y - XR(4 * i + 1);
                    float e2 = q.z - XR(4 * i + 2);
                    float e3 = q.w - XR(4 * i + 3);
                    err = fmaf(e0, e0, err);
                    err = fmaf(e1, e1, err);
                    err = fmaf(e2, e2, err);
                    err = fmaf(e3, e3, err);
                    oq[i] = q;
                }
                out[OUT_IDX + t] = (float)bi;
                atomicAdd(&counts[bi], 1u);
            }
#pragma unroll
            for (int o = 32; o > 0; o >>= 1) err += __shfl_down(err, o, 64);
            if (lane == 0) atomicAdd(sse, err);
        }
        __syncthreads();
    }
}
#undef XR

// ---------------------------------------------------------------------------
__global__ void vq_fin(const unsigned* __restrict__ counts,
                       const float* __restrict__ sse,
                       float* __restrict__ out) {
    __shared__ float red[256];
    float s = 0.f;
    for (int k = threadIdx.x; k < K; k += 256) {
        float p = (float)counts[k] * (1.0f / (float)N_TOK);
        s += p * logf(p + 1e-10f);
    }
    red[threadIdx.x] = s;
    __syncthreads();
    for (int st = 128; st > 0; st >>= 1) {
        if (threadIdx.x < st) red[threadIdx.x] += red[threadIdx.x + st];
        __syncthreads();
    }
    if (threadIdx.x == 0) {
        out[OUT_PERP] = expf(-red[0]);
        out[OUT_LOSS] = 1.25f * (*sse) * (1.0f / 8388608.0f);  // (1+0.25)*MSE
    }
}

// ---------------------------------------------------------------------------
extern "C" void kernel_launch(void* const* d_in, const int* in_sizes, int n_in,
                              void* d_out, int out_size, void* d_ws, size_t ws_size,
                              hipStream_t stream) {
    const float* x = (const float*)d_in[0];  // [32,64,64,64] fp32
    const float* w = (const float*)d_in[1];  // [1024,64] fp32
    float* out = (float*)d_out;

    char* ws = (char*)d_ws;
    unsigned* counts = (unsigned*)(ws + 0);
    float*    enorm  = (float*)(ws + 4096);
    float*    sinit  = (float*)(ws + 8192);
    float*    sse    = (float*)(ws + 12288);
    unsigned* rcnt   = (unsigned*)(ws + 12292);
    short*    w_hi   = (short*)(ws + 16384);
    short*    w_lo   = (short*)(ws + 147456);
    int*      win    = (int*)(ws + 278528);
    int*      rlist  = (int*)(ws + 802816);

    vq_prep<<<4, 256, 0, stream>>>(w, enorm, sinit, w_hi, w_lo, counts, sse, rcnt);
    vq_screen<<<N_TOK / 128, 256, 0, stream>>>(x, sinit, w_hi, w_lo, win);
    vq_epi<<<N_TOK / 256, 256, 0, stream>>>(x, w, win, out, counts, sse, rlist, rcnt);
    vq_rescue<<<256, 1024, 0, stream>>>(x, w, enorm, out, counts, sse, rlist, rcnt);
    vq_fin<<<1, 256, 0, stream>>>(counts, sse, out);
}

// Round 4
// 256.001 us; speedup vs baseline: 2.0423x; 1.2665x over previous
//
#include <hip/hip_runtime.h>
#include <math.h>

// Problem constants
#define N_TOK 131072   // 32*64*64 tokens
#define D     64       // embedding dim
#define K     1024     // codebook size

// Output layout (floats, concatenated in reference return order):
#define OUT_LOSS  8388608
#define OUT_IDX   8388609
#define OUT_PERP  8519681

// ws layout (bytes):
//   0        counts  u32[1024]
//   4096     enorm   f32[1024]  np-exact ||e||^2
//   8192     sinit   f32[1024]  fp64-accurate ||e||^2 (screen C-init)
//   12288    sse     f32
//   12292    rcnt    u32        rescue-list counter
//   16384    w_hi    s16[65536] bf16 hi split of w (128 KB)
//   147456   w_lo    s16[65536] bf16 lo split of w (128 KB)
//   278528   win     i32[131072] packed winner (bit31 = needs rescue)
//   802816   rlist   i32[131072] compacted rescue token ids

#define W_WINDOW 1e-4f

typedef short bf16x8 __attribute__((ext_vector_type(8)));
typedef float f32x4  __attribute__((ext_vector_type(4)));
typedef float vf16   __attribute__((ext_vector_type(16)));

// LDS byte-offset swizzle: XOR bits 4-6 with row bits (byte>>7)&7.
// Involution; applied on BOTH ds_write (staging) and ds_read (fragments).
// Kills the 16-way bank conflict of row-major [code][128B] fragment reads.
#define SWZ(p) ((p) ^ ((((p) >> 7) & 7) << 4))

// ---------------------------------------------------------------------------
__device__ __forceinline__ float np_pairsum64(const float* sq) {
    float r[8];
#pragma unroll
    for (int j = 0; j < 8; ++j) r[j] = sq[j];
#pragma unroll
    for (int i = 8; i < 64; i += 8) {
#pragma unroll
        for (int j = 0; j < 8; ++j) r[j] = __fadd_rn(r[j], sq[i + j]);
    }
    return __fadd_rn(
        __fadd_rn(__fadd_rn(r[0], r[1]), __fadd_rn(r[2], r[3])),
        __fadd_rn(__fadd_rn(r[4], r[5]), __fadd_rn(r[6], r[7])));
}

__device__ __forceinline__ short bf16_trunc(float f) {
    return (short)(__float_as_uint(f) >> 16);
}
__device__ __forceinline__ float bf16_up(short s) {
    return __uint_as_float(((unsigned)(unsigned short)s) << 16);
}

// ---------------------------------------------------------------------------
__global__ void vq_prep(const float* __restrict__ w,
                        float* __restrict__ enorm,
                        float* __restrict__ sinit,
                        short* __restrict__ w_hi,
                        short* __restrict__ w_lo,
                        unsigned* __restrict__ counts,
                        float* __restrict__ sse,
                        unsigned* __restrict__ rcnt) {
    int k = blockIdx.x * blockDim.x + threadIdx.x;
    if (k < K) {
        const float* wr = w + (size_t)k * D;
        float sq[D];
        double acc = 0.0;
#pragma unroll
        for (int i = 0; i < D; ++i) {
            float v = wr[i];
            sq[i] = __fmul_rn(v, v);
            acc += (double)v * (double)v;
            short hi = bf16_trunc(v);
            float res = v - bf16_up(hi);
            short lo = bf16_trunc(res);
            w_hi[(size_t)k * D + i] = hi;
            w_lo[(size_t)k * D + i] = lo;
        }
        enorm[k] = np_pairsum64(sq);
        sinit[k] = (float)acc;
        counts[k] = 0u;
    }
    if (k == 0) { *sse = 0.f; *rcnt = 0u; }
}

// ---------------------------------------------------------------------------
// Screen with canonical LDS staging (round-0 math, bit-identical order).
// Every wave previously streamed the full 256 KB codebook from L2 (1 GB of
// L2->CU traffic, L1-thrashing, ~87% stall). Now each block stages 4-tile
// chunks (64 codes, hi+lo = 16 KB) into double-buffered LDS (32 KB/block,
// 4 blocks/CU preserved) and the 4 waves share them via conflict-free
// swizzled ds_read_b128. Staging: global->reg (issued before compute(c)) ->
// ds_write after compute (T14 split), one barrier per chunk.
// ---------------------------------------------------------------------------
#define MFMA(A, B, C) __builtin_amdgcn_mfma_f32_16x16x32_bf16(A, B, C, 0, 0, 0)

__device__ __forceinline__ void tile_step(
    int code, const bf16x8 (&Ah)[2][2], const bf16x8 (&Al)[2][2],
    bf16x8 H0, bf16x8 H1, bf16x8 L0, bf16x8 L1, float si,
    float (&m1)[8], float (&m2)[8], int (&i1)[8]) {
    f32x4 C0 = {si, si, si, si};
    f32x4 C1 = {si, si, si, si};
    C0 = MFMA(Ah[0][0], H0, C0); C0 = MFMA(Ah[0][1], H1, C0);
    C0 = MFMA(Ah[0][0], L0, C0); C0 = MFMA(Ah[0][1], L1, C0);
    C0 = MFMA(Al[0][0], H0, C0); C0 = MFMA(Al[0][1], H1, C0);
    C1 = MFMA(Ah[1][0], H0, C1); C1 = MFMA(Ah[1][1], H1, C1);
    C1 = MFMA(Ah[1][0], L0, C1); C1 = MFMA(Ah[1][1], L1, C1);
    C1 = MFMA(Al[1][0], H0, C1); C1 = MFMA(Al[1][1], H1, C1);
#pragma unroll
    for (int r = 0; r < 4; ++r) {
        {
            float c = C0[r];
            // med3(m1,m2,c) == min(m2, max(m1,c)) given m1<=m2 (exact select)
            m2[r] = __builtin_amdgcn_fmed3f(m1[r], m2[r], c);
            bool lt = c < m1[r];
            i1[r] = lt ? code : i1[r];
            m1[r] = fminf(m1[r], c);
        }
        {
            float c = C1[r];
            m2[4 + r] = __builtin_amdgcn_fmed3f(m1[4 + r], m2[4 + r], c);
            bool lt = c < m1[4 + r];
            i1[4 + r] = lt ? code : i1[4 + r];
            m1[4 + r] = fminf(m1[4 + r], c);
        }
    }
}

__global__ __launch_bounds__(256, 4)
void vq_screen(const float* __restrict__ x,
               const float* __restrict__ sinit,
               const short* __restrict__ w_hi,
               const short* __restrict__ w_lo,
               int* __restrict__ win) {
    const int tid  = threadIdx.x;
    const int lane = tid & 63;
    const int wv   = __builtin_amdgcn_readfirstlane(tid >> 6);
    const int quad = lane >> 4;
    const int col  = lane & 15;
    const int tokWave = blockIdx.x * 128 + wv * 32;

    // [buf][hi/lo][64 codes * 64 dims] = 32 KB
    __shared__ short sB[2][2][4096];

    bf16x8 Ah[2][2], Al[2][2];
#pragma unroll
    for (int mt = 0; mt < 2; ++mt) {
#pragma unroll
        for (int ks = 0; ks < 2; ++ks) {
            const float4* ap = (const float4*)(x + (size_t)(tokWave + mt * 16 + col) * D
                                               + ks * 32 + quad * 8);
            float4 u0 = ap[0], u1 = ap[1];
            float f[8] = {u0.x, u0.y, u0.z, u0.w, u1.x, u1.y, u1.z, u1.w};
            bf16x8 h, l;
#pragma unroll
            for (int j = 0; j < 8; ++j) {
                float v = -2.0f * f[j];
                short hi = bf16_trunc(v);
                float res = v - bf16_up(hi);
                h[j] = hi;
                l[j] = bf16_trunc(res);
            }
            Ah[mt][ks] = h;
            Al[mt][ks] = l;
        }
    }

    float m1[8], m2[8];
    int   i1[8];
#pragma unroll
    for (int s = 0; s < 8; ++s) { m1[s] = INFINITY; m2[s] = INFINITY; i1[s] = 0; }

    // Staging geometry: chunk = 64 codes = 8192 B per array (hi, lo).
    // Thread stages 16 B at linear offset p0 and p0+4096 from each array;
    // ds_write goes to SWZ(p) in the destination buffer.
    const int  p0 = tid * 16;
    const int  p1 = p0 + 4096;
    const char* gh = (const char*)w_hi;
    const char* gl = (const char*)w_lo;

    // Initial stage: chunk 0 -> buf 0
    {
        float4 g0 = *(const float4*)(gh + p0);
        float4 g1 = *(const float4*)(gh + p1);
        float4 g2 = *(const float4*)(gl + p0);
        float4 g3 = *(const float4*)(gl + p1);
        char* lh = (char*)&sB[0][0][0];
        char* ll = (char*)&sB[0][1][0];
        *(float4*)(lh + SWZ(p0)) = g0;
        *(float4*)(lh + SWZ(p1)) = g1;
        *(float4*)(ll + SWZ(p0)) = g2;
        *(float4*)(ll + SWZ(p1)) = g3;
    }
    __syncthreads();

    for (int c = 0; c < 16; ++c) {
        const int buf = c & 1;
        const bool pf = (c < 15);
        float4 g0, g1, g2, g3;
        if (pf) {
            const size_t cb = (size_t)(c + 1) * 8192;
            g0 = *(const float4*)(gh + cb + p0);
            g1 = *(const float4*)(gh + cb + p1);
            g2 = *(const float4*)(gl + cb + p0);
            g3 = *(const float4*)(gl + cb + p1);
        }

        const char* lh = (const char*)&sB[buf][0][0];
        const char* ll = (const char*)&sB[buf][1][0];
#pragma unroll
        for (int tl = 0; tl < 4; ++tl) {
            const int r_ = tl * 16 + col;          // code row within chunk
            const int b0 = r_ * 128 + quad * 16;
            const int b1 = b0 + 64;
            bf16x8 H0 = *(const bf16x8*)(lh + SWZ(b0));
            bf16x8 H1 = *(const bf16x8*)(lh + SWZ(b1));
            bf16x8 L0 = *(const bf16x8*)(ll + SWZ(b0));
            bf16x8 L1 = *(const bf16x8*)(ll + SWZ(b1));
            const int tile = c * 4 + tl;
            const float si = sinit[tile * 16 + col];
            tile_step(tile * 16 + col, Ah, Al, H0, H1, L0, L1, si, m1, m2, i1);
        }

        if (pf) {
            char* dh = (char*)&sB[buf ^ 1][0][0];
            char* dl = (char*)&sB[buf ^ 1][1][0];
            *(float4*)(dh + SWZ(p0)) = g0;
            *(float4*)(dh + SWZ(p1)) = g1;
            *(float4*)(dl + SWZ(p0)) = g2;
            *(float4*)(dl + SWZ(p1)) = g3;
        }
        __syncthreads();
    }

#pragma unroll
    for (int s = 0; s < 8; ++s) {
#pragma unroll
        for (int msk = 1; msk <= 8; msk <<= 1) {
            float om1 = __shfl_xor(m1[s], msk, 64);
            int   oi1 = __shfl_xor(i1[s], msk, 64);
            float om2 = __shfl_xor(m2[s], msk, 64);
            float nm2 = fminf(fmaxf(m1[s], om1), fminf(m2[s], om2));
            bool  take = om1 < m1[s];
            m1[s] = take ? om1 : m1[s];
            i1[s] = take ? oi1 : i1[s];
            m2[s] = nm2;
        }
    }

    if (col == 0) {
#pragma unroll
        for (int s = 0; s < 8; ++s) {
            int tl = (s >> 2) * 16 + quad * 4 + (s & 3);
            bool resc = (m2[s] <= m1[s] + W_WINDOW);
            win[tokWave + tl] = resc ? (i1[s] | 0x80000000) : i1[s];
        }
    }
}
#undef MFMA

// ---------------------------------------------------------------------------
// Epilogue. Phase A (1 thread/token): unpack win[], rescue flag -> rlist,
// else counts+idx. Phase B (16 lanes/token): fully-coalesced gather+write+SSE
// (64 lanes = 4 consecutive tokens = 1 KB contiguous per wave instruction).
// ---------------------------------------------------------------------------
__global__ __launch_bounds__(256, 4)
void vq_epi(const float* __restrict__ x,
            const float* __restrict__ w,
            const int* __restrict__ win,
            float* __restrict__ out,
            unsigned* __restrict__ counts,
            float* __restrict__ sse,
            int* __restrict__ rlist,
            unsigned* __restrict__ rcnt) {
    __shared__ int smw[256];
    const int t = blockIdx.x * 256 + threadIdx.x;

    const int wi = win[t];
    if (wi < 0) {
        unsigned u = atomicAdd(rcnt, 1u);
        rlist[u] = t;
        smw[threadIdx.x] = -1;
    } else {
        atomicAdd(&counts[wi], 1u);
        out[OUT_IDX + t] = (float)wi;
        smw[threadIdx.x] = wi;
    }
    __syncthreads();

    // Phase B: coalesced copy + SSE
    const int lane = threadIdx.x & 63;
    const int wvi  = threadIdx.x >> 6;
    const int sub  = lane >> 4;         // token within 4-token pass
    const int i    = lane & 15;         // float4 index within 64-float row
    float err = 0.f;
#pragma unroll
    for (int p = 0; p < 16; ++p) {
        const int tl  = wvi * 64 + p * 4 + sub;          // local token 0..255
        const int tok = blockIdx.x * 256 + tl;
        const int wi2 = smw[tl];
        if (wi2 >= 0) {
            float4 q  = ((const float4*)(w + (size_t)wi2 * D))[i];
            float4 xv = ((const float4*)(x + (size_t)tok * D))[i];
            float e0 = q.x - xv.x, e1 = q.y - xv.y;
            float e2 = q.z - xv.z, e3 = q.w - xv.w;
            err = fmaf(e0, e0, err);
            err = fmaf(e1, e1, err);
            err = fmaf(e2, e2, err);
            err = fmaf(e3, e3, err);
            ((float4*)(out + (size_t)tok * D))[i] = q;
        }
    }
#pragma unroll
    for (int o = 32; o > 0; o >>= 1) err += __shfl_down(err, o, 64);
    if (lane == 0) atomicAdd(sse, err);
}

// ---------------------------------------------------------------------------
// Rescue v2 (round-5-verified structure on the compacted list).
// Block = 1024 threads = 16 waves = 64 tokens (lane = token); wave wv scans
// codes [wv*64, wv*64+64) with the np-exact fp32 chain, wave-uniform scalar
// w loads. LDS first-min combine in ascending chunk order == np.argmin.
// ---------------------------------------------------------------------------
#define XR(d) ((d) < 16 ? xa[(d) & 15] : (d) < 32 ? xb[(d) & 15] \
              : (d) < 48 ? xc[(d) & 15] : xd[(d) & 15])

__global__ __launch_bounds__(1024, 1)
void vq_rescue(const float* __restrict__ x,
               const float* __restrict__ w,
               const float* __restrict__ enorm,
               float* __restrict__ out,
               unsigned* __restrict__ counts,
               float* __restrict__ sse,
               const int* __restrict__ rlist,
               const unsigned* __restrict__ rcnt) {
    const int lane = threadIdx.x & 63;
    const int wv   = __builtin_amdgcn_readfirstlane(threadIdx.x >> 6);  // 0..15
    const unsigned n = *rcnt;

    __shared__ float sd[16][64];
    __shared__ int   si[16][64];

    for (unsigned g = blockIdx.x; g * 64u < n; g += 256u) {
        const unsigned slot = g * 64u + (unsigned)lane;
        const bool valid = slot < n;
        const int t = valid ? rlist[slot] : 0;

        // Token row in 4 SSA vectors.
        const vf16* xp = (const vf16*)(x + (size_t)t * D);
        vf16 xa = xp[0], xb = xp[1], xc = xp[2], xd = xp[3];

        // Sx np-exact (8 accumulators, ascending blocks, pairwise tail).
        float Sx;
        {
            float r0, r1, r2, r3, r4, r5, r6, r7;
#define SQ(n) __fmul_rn(XR(n), XR(n))
            r0 = SQ(0); r1 = SQ(1); r2 = SQ(2); r3 = SQ(3);
            r4 = SQ(4); r5 = SQ(5); r6 = SQ(6); r7 = SQ(7);
#define ACC8(i)                                                           \
            r0 = __fadd_rn(r0, SQ(8*(i)+0)); r1 = __fadd_rn(r1, SQ(8*(i)+1)); \
            r2 = __fadd_rn(r2, SQ(8*(i)+2)); r3 = __fadd_rn(r3, SQ(8*(i)+3)); \
            r4 = __fadd_rn(r4, SQ(8*(i)+4)); r5 = __fadd_rn(r5, SQ(8*(i)+5)); \
            r6 = __fadd_rn(r6, SQ(8*(i)+6)); r7 = __fadd_rn(r7, SQ(8*(i)+7));
            ACC8(1) ACC8(2) ACC8(3) ACC8(4) ACC8(5) ACC8(6) ACC8(7)
            Sx = __fadd_rn(
                __fadd_rn(__fadd_rn(r0, r1), __fadd_rn(r2, r3)),
                __fadd_rn(__fadd_rn(r4, r5), __fadd_rn(r6, r7)));
#undef ACC8
#undef SQ
        }

        // np-exact scan of this wave's 64-code chunk (c ascending).
        float best = INFINITY;
        int   bidx = 0x7fffffff;
        const int c0 = wv * 64;
        for (int cc = 0; cc < 64; ++cc) {
            const int c = c0 + cc;
            const float* __restrict__ wr = w + (size_t)c * D;  // wave-uniform
            float a = 0.f;
#pragma unroll
            for (int d = 0; d < D; ++d) a = __fmaf_rn(wr[d], XR(d), a);
            float dist = __fsub_rn(__fadd_rn(Sx, enorm[c]), __fmul_rn(2.0f, a));
            bool lt = dist < best;  // strict <: first-min within chunk
            best = lt ? dist : best;
            bidx = lt ? c : bidx;
        }
        sd[wv][lane] = best;
        si[wv][lane] = bidx;
        __syncthreads();

        if (wv == 0) {
            float b  = sd[0][lane];
            int   bi = si[0][lane];
#pragma unroll
            for (int j = 1; j < 16; ++j) {
                float dj = sd[j][lane];
                bool  l  = dj < b;  // strict <: lower chunk (lower idx) wins ties
                b  = l ? dj : b;
                bi = l ? si[j][lane] : bi;
            }

            float err = 0.f;
            if (valid) {
                const float4* qr = (const float4*)(w + (size_t)bi * D);
                float4*       oq = (float4*)(out + (size_t)t * D);
#pragma unroll
                for (int i = 0; i < 16; ++i) {
                    float4 q = qr[i];
                    float e0 = q.x - XR(4 * i + 0);
                    float e1 = q.y - XR(4 * i + 1);
                    float e2 = q.z - XR(4 * i + 2);
                    float e3 = q.w - XR(4 * i + 3);
                    err = fmaf(e0, e0, err);
                    err = fmaf(e1, e1, err);
                    err = fmaf(e2, e2, err);
                    err = fmaf(e3, e3, err);
                    oq[i] = q;
                }
                out[OUT_IDX + t] = (float)bi;
                atomicAdd(&counts[bi], 1u);
            }
#pragma unroll
            for (int o = 32; o > 0; o >>= 1) err += __shfl_down(err, o, 64);
            if (lane == 0) atomicAdd(sse, err);
        }
        __syncthreads();
    }
}
#undef XR

// ---------------------------------------------------------------------------
__global__ void vq_fin(const unsigned* __restrict__ counts,
                       const float* __restrict__ sse,
                       float* __restrict__ out) {
    __shared__ float red[256];
    float s = 0.f;
    for (int k = threadIdx.x; k < K; k += 256) {
        float p = (float)counts[k] * (1.0f / (float)N_TOK);
        s += p * logf(p + 1e-10f);
    }
    red[threadIdx.x] = s;
    __syncthreads();
    for (int st = 128; st > 0; st >>= 1) {
        if (threadIdx.x < st) red[threadIdx.x] += red[threadIdx.x + st];
        __syncthreads();
    }
    if (threadIdx.x == 0) {
        out[OUT_PERP] = expf(-red[0]);
        out[OUT_LOSS] = 1.25f * (*sse) * (1.0f / 8388608.0f);  // (1+0.25)*MSE
    }
}

// ---------------------------------------------------------------------------
extern "C" void kernel_launch(void* const* d_in, const int* in_sizes, int n_in,
                              void* d_out, int out_size, void* d_ws, size_t ws_size,
                              hipStream_t stream) {
    const float* x = (const float*)d_in[0];  // [32,64,64,64] fp32
    const float* w = (const float*)d_in[1];  // [1024,64] fp32
    float* out = (float*)d_out;

    char* ws = (char*)d_ws;
    unsigned* counts = (unsigned*)(ws + 0);
    float*    enorm  = (float*)(ws + 4096);
    float*    sinit  = (float*)(ws + 8192);
    float*    sse    = (float*)(ws + 12288);
    unsigned* rcnt   = (unsigned*)(ws + 12292);
    short*    w_hi   = (short*)(ws + 16384);
    short*    w_lo   = (short*)(ws + 147456);
    int*      win    = (int*)(ws + 278528);
    int*      rlist  = (int*)(ws + 802816);

    vq_prep<<<4, 256, 0, stream>>>(w, enorm, sinit, w_hi, w_lo, counts, sse, rcnt);
    vq_screen<<<N_TOK / 128, 256, 0, stream>>>(x, sinit, w_hi, w_lo, win);
    vq_epi<<<N_TOK / 256, 256, 0, stream>>>(x, w, win, out, counts, sse, rlist, rcnt);
    vq_rescue<<<256, 1024, 0, stream>>>(x, w, enorm, out, counts, sse, rlist, rcnt);
    vq_fin<<<1, 256, 0, stream>>>(counts, sse, out);
}

// Round 5
// 248.851 us; speedup vs baseline: 2.1010x; 1.0287x over previous
//
#include <hip/hip_runtime.h>
#include <math.h>

// Problem constants
#define N_TOK 131072   // 32*64*64 tokens
#define D     64       // embedding dim
#define K     1024     // codebook size

// Output layout (floats, concatenated in reference return order):
#define OUT_LOSS  8388608
#define OUT_IDX   8388609
#define OUT_PERP  8519681

// ws layout (bytes):
//   0        counts  u32[1024]
//   4096     enorm   f32[1024]  np-exact ||e||^2
//   8192     sinit   f32[1024]  fp64-accurate ||e||^2 (screen C-init)
//   12288    sse     f32
//   12292    rcnt    u32        rescue-list counter
//   16384    w_hi    s16[65536] bf16 hi split of w (128 KB)
//   147456   w_lo    s16[65536] bf16 lo split of w (128 KB)
//   278528   win     i32[131072] packed winner (bit31 = needs rescue)
//   802816   rlist   i32[131072] compacted rescue token ids

#define W_WINDOW 1e-4f

typedef short bf16x8 __attribute__((ext_vector_type(8)));
typedef float f32x4  __attribute__((ext_vector_type(4)));
typedef float vf16   __attribute__((ext_vector_type(16)));

// LDS byte-offset swizzle: XOR bits 4-6 with row bits (byte>>7)&7.
// Involution; applied on BOTH ds_write (staging) and ds_read (fragments).
// Kills the 16-way bank conflict of row-major [code][128B] fragment reads.
#define SWZ(p) ((p) ^ ((((p) >> 7) & 7) << 4))

// ---------------------------------------------------------------------------
__device__ __forceinline__ float np_pairsum64(const float* sq) {
    float r[8];
#pragma unroll
    for (int j = 0; j < 8; ++j) r[j] = sq[j];
#pragma unroll
    for (int i = 8; i < 64; i += 8) {
#pragma unroll
        for (int j = 0; j < 8; ++j) r[j] = __fadd_rn(r[j], sq[i + j]);
    }
    return __fadd_rn(
        __fadd_rn(__fadd_rn(r[0], r[1]), __fadd_rn(r[2], r[3])),
        __fadd_rn(__fadd_rn(r[4], r[5]), __fadd_rn(r[6], r[7])));
}

__device__ __forceinline__ short bf16_trunc(float f) {
    return (short)(__float_as_uint(f) >> 16);
}
__device__ __forceinline__ float bf16_up(short s) {
    return __uint_as_float(((unsigned)(unsigned short)s) << 16);
}

// ---------------------------------------------------------------------------
__global__ void vq_prep(const float* __restrict__ w,
                        float* __restrict__ enorm,
                        float* __restrict__ sinit,
                        short* __restrict__ w_hi,
                        short* __restrict__ w_lo,
                        unsigned* __restrict__ counts,
                        float* __restrict__ sse,
                        unsigned* __restrict__ rcnt) {
    int k = blockIdx.x * blockDim.x + threadIdx.x;
    if (k < K) {
        const float* wr = w + (size_t)k * D;
        float sq[D];
        double acc = 0.0;
#pragma unroll
        for (int i = 0; i < D; ++i) {
            float v = wr[i];
            sq[i] = __fmul_rn(v, v);
            acc += (double)v * (double)v;
            short hi = bf16_trunc(v);
            float res = v - bf16_up(hi);
            short lo = bf16_trunc(res);
            w_hi[(size_t)k * D + i] = hi;
            w_lo[(size_t)k * D + i] = lo;
        }
        enorm[k] = np_pairsum64(sq);
        sinit[k] = (float)acc;
        counts[k] = 0u;
    }
    if (k == 0) { *sse = 0.f; *rcnt = 0u; }
}

// ---------------------------------------------------------------------------
// Screen with canonical LDS staging (round-0 math, bit-identical order).
// Each block stages 4-tile chunks (64 codes, hi+lo = 16 KB) into
// double-buffered LDS (32 KB/block, 4 blocks/CU) and the 4 waves share them
// via conflict-free swizzled ds_read_b128.
// ---------------------------------------------------------------------------
#define MFMA(A, B, C) __builtin_amdgcn_mfma_f32_16x16x32_bf16(A, B, C, 0, 0, 0)

__device__ __forceinline__ void tile_step(
    int code, const bf16x8 (&Ah)[2][2], const bf16x8 (&Al)[2][2],
    bf16x8 H0, bf16x8 H1, bf16x8 L0, bf16x8 L1, float si,
    float (&m1)[8], float (&m2)[8], int (&i1)[8]) {
    f32x4 C0 = {si, si, si, si};
    f32x4 C1 = {si, si, si, si};
    C0 = MFMA(Ah[0][0], H0, C0); C0 = MFMA(Ah[0][1], H1, C0);
    C0 = MFMA(Ah[0][0], L0, C0); C0 = MFMA(Ah[0][1], L1, C0);
    C0 = MFMA(Al[0][0], H0, C0); C0 = MFMA(Al[0][1], H1, C0);
    C1 = MFMA(Ah[1][0], H0, C1); C1 = MFMA(Ah[1][1], H1, C1);
    C1 = MFMA(Ah[1][0], L0, C1); C1 = MFMA(Ah[1][1], L1, C1);
    C1 = MFMA(Al[1][0], H0, C1); C1 = MFMA(Al[1][1], H1, C1);
#pragma unroll
    for (int r = 0; r < 4; ++r) {
        {
            float c = C0[r];
            // med3(m1,m2,c) == min(m2, max(m1,c)) given m1<=m2 (exact select)
            m2[r] = __builtin_amdgcn_fmed3f(m1[r], m2[r], c);
            bool lt = c < m1[r];
            i1[r] = lt ? code : i1[r];
            m1[r] = fminf(m1[r], c);
        }
        {
            float c = C1[r];
            m2[4 + r] = __builtin_amdgcn_fmed3f(m1[4 + r], m2[4 + r], c);
            bool lt = c < m1[4 + r];
            i1[4 + r] = lt ? code : i1[4 + r];
            m1[4 + r] = fminf(m1[4 + r], c);
        }
    }
}

__global__ __launch_bounds__(256, 4)
void vq_screen(const float* __restrict__ x,
               const float* __restrict__ sinit,
               const short* __restrict__ w_hi,
               const short* __restrict__ w_lo,
               int* __restrict__ win) {
    const int tid  = threadIdx.x;
    const int lane = tid & 63;
    const int wv   = __builtin_amdgcn_readfirstlane(tid >> 6);
    const int quad = lane >> 4;
    const int col  = lane & 15;
    const int tokWave = blockIdx.x * 128 + wv * 32;

    // [buf][hi/lo][64 codes * 64 dims] = 32 KB
    __shared__ short sB[2][2][4096];

    bf16x8 Ah[2][2], Al[2][2];
#pragma unroll
    for (int mt = 0; mt < 2; ++mt) {
#pragma unroll
        for (int ks = 0; ks < 2; ++ks) {
            const float4* ap = (const float4*)(x + (size_t)(tokWave + mt * 16 + col) * D
                                               + ks * 32 + quad * 8);
            float4 u0 = ap[0], u1 = ap[1];
            float f[8] = {u0.x, u0.y, u0.z, u0.w, u1.x, u1.y, u1.z, u1.w};
            bf16x8 h, l;
#pragma unroll
            for (int j = 0; j < 8; ++j) {
                float v = -2.0f * f[j];
                short hi = bf16_trunc(v);
                float res = v - bf16_up(hi);
                h[j] = hi;
                l[j] = bf16_trunc(res);
            }
            Ah[mt][ks] = h;
            Al[mt][ks] = l;
        }
    }

    float m1[8], m2[8];
    int   i1[8];
#pragma unroll
    for (int s = 0; s < 8; ++s) { m1[s] = INFINITY; m2[s] = INFINITY; i1[s] = 0; }

    // Staging geometry: chunk = 64 codes = 8192 B per array (hi, lo).
    const int  p0 = tid * 16;
    const int  p1 = p0 + 4096;
    const char* gh = (const char*)w_hi;
    const char* gl = (const char*)w_lo;

    // Initial stage: chunk 0 -> buf 0
    {
        float4 g0 = *(const float4*)(gh + p0);
        float4 g1 = *(const float4*)(gh + p1);
        float4 g2 = *(const float4*)(gl + p0);
        float4 g3 = *(const float4*)(gl + p1);
        char* lh = (char*)&sB[0][0][0];
        char* ll = (char*)&sB[0][1][0];
        *(float4*)(lh + SWZ(p0)) = g0;
        *(float4*)(lh + SWZ(p1)) = g1;
        *(float4*)(ll + SWZ(p0)) = g2;
        *(float4*)(ll + SWZ(p1)) = g3;
    }
    __syncthreads();

    for (int c = 0; c < 16; ++c) {
        const int buf = c & 1;
        const bool pf = (c < 15);
        float4 g0, g1, g2, g3;
        if (pf) {
            const size_t cb = (size_t)(c + 1) * 8192;
            g0 = *(const float4*)(gh + cb + p0);
            g1 = *(const float4*)(gh + cb + p1);
            g2 = *(const float4*)(gl + cb + p0);
            g3 = *(const float4*)(gl + cb + p1);
        }

        const char* lh = (const char*)&sB[buf][0][0];
        const char* ll = (const char*)&sB[buf][1][0];
#pragma unroll
        for (int tl = 0; tl < 4; ++tl) {
            const int r_ = tl * 16 + col;          // code row within chunk
            const int b0 = r_ * 128 + quad * 16;
            const int b1 = b0 + 64;
            bf16x8 H0 = *(const bf16x8*)(lh + SWZ(b0));
            bf16x8 H1 = *(const bf16x8*)(lh + SWZ(b1));
            bf16x8 L0 = *(const bf16x8*)(ll + SWZ(b0));
            bf16x8 L1 = *(const bf16x8*)(ll + SWZ(b1));
            const int tile = c * 4 + tl;
            const float si = sinit[tile * 16 + col];
            tile_step(tile * 16 + col, Ah, Al, H0, H1, L0, L1, si, m1, m2, i1);
        }

        if (pf) {
            char* dh = (char*)&sB[buf ^ 1][0][0];
            char* dl = (char*)&sB[buf ^ 1][1][0];
            *(float4*)(dh + SWZ(p0)) = g0;
            *(float4*)(dh + SWZ(p1)) = g1;
            *(float4*)(dl + SWZ(p0)) = g2;
            *(float4*)(dl + SWZ(p1)) = g3;
        }
        __syncthreads();
    }

#pragma unroll
    for (int s = 0; s < 8; ++s) {
#pragma unroll
        for (int msk = 1; msk <= 8; msk <<= 1) {
            float om1 = __shfl_xor(m1[s], msk, 64);
            int   oi1 = __shfl_xor(i1[s], msk, 64);
            float om2 = __shfl_xor(m2[s], msk, 64);
            float nm2 = fminf(fmaxf(m1[s], om1), fminf(m2[s], om2));
            bool  take = om1 < m1[s];
            m1[s] = take ? om1 : m1[s];
            i1[s] = take ? oi1 : i1[s];
            m2[s] = nm2;
        }
    }

    if (col == 0) {
#pragma unroll
        for (int s = 0; s < 8; ++s) {
            int tl = (s >> 2) * 16 + quad * 4 + (s & 3);
            bool resc = (m2[s] <= m1[s] + W_WINDOW);
            win[tokWave + tl] = resc ? (i1[s] | 0x80000000) : i1[s];
        }
    }
}
#undef MFMA

// ---------------------------------------------------------------------------
// Epilogue. Phase A (1 thread/token): unpack win[], rescue flag -> rlist,
// else counts+idx. Phase B (16 lanes/token): fully-coalesced gather+write+SSE
// (64 lanes = 4 consecutive tokens = 1 KB contiguous per wave instruction).
// ---------------------------------------------------------------------------
__global__ __launch_bounds__(256, 4)
void vq_epi(const float* __restrict__ x,
            const float* __restrict__ w,
            const int* __restrict__ win,
            float* __restrict__ out,
            unsigned* __restrict__ counts,
            float* __restrict__ sse,
            int* __restrict__ rlist,
            unsigned* __restrict__ rcnt) {
    __shared__ int smw[256];
    const int t = blockIdx.x * 256 + threadIdx.x;

    const int wi = win[t];
    if (wi < 0) {
        unsigned u = atomicAdd(rcnt, 1u);
        rlist[u] = t;
        smw[threadIdx.x] = -1;
    } else {
        atomicAdd(&counts[wi], 1u);
        out[OUT_IDX + t] = (float)wi;
        smw[threadIdx.x] = wi;
    }
    __syncthreads();

    // Phase B: coalesced copy + SSE
    const int lane = threadIdx.x & 63;
    const int wvi  = threadIdx.x >> 6;
    const int sub  = lane >> 4;         // token within 4-token pass
    const int i    = lane & 15;         // float4 index within 64-float row
    float err = 0.f;
#pragma unroll
    for (int p = 0; p < 16; ++p) {
        const int tl  = wvi * 64 + p * 4 + sub;          // local token 0..255
        const int tok = blockIdx.x * 256 + tl;
        const int wi2 = smw[tl];
        if (wi2 >= 0) {
            float4 q  = ((const float4*)(w + (size_t)wi2 * D))[i];
            float4 xv = ((const float4*)(x + (size_t)tok * D))[i];
            float e0 = q.x - xv.x, e1 = q.y - xv.y;
            float e2 = q.z - xv.z, e3 = q.w - xv.w;
            err = fmaf(e0, e0, err);
            err = fmaf(e1, e1, err);
            err = fmaf(e2, e2, err);
            err = fmaf(e3, e3, err);
            ((float4*)(out + (size_t)tok * D))[i] = q;
        }
    }
#pragma unroll
    for (int o = 32; o > 0; o >>= 1) err += __shfl_down(err, o, 64);
    if (lane == 0) atomicAdd(sse, err);
}

// ---------------------------------------------------------------------------
// Rescue v3: identical math/semantics to v2, repartitioned for registers.
// Round-4 counters showed VGPR_Count=64 with the 1024-thread block: the
// token's x row (vf16 xa..xd = 64 VGPRs) spilled to scratch, and the hot
// 64-FMA chain re-read x from scratch every code (83 us, 10% VALU).
// Now: 512 threads = 8 waves (2 waves/SIMD -> 256-VGPR budget, no spill),
// wave wv scans codes [wv*128, wv*128+128) ascending. LDS first-min combine
// over 8 chunks ascending == np.argmin, bit-identical to v2.
// ---------------------------------------------------------------------------
#define XR(d) ((d) < 16 ? xa[(d) & 15] : (d) < 32 ? xb[(d) & 15] \
              : (d) < 48 ? xc[(d) & 15] : xd[(d) & 15])

__global__ __launch_bounds__(512, 2)
void vq_rescue(const float* __restrict__ x,
               const float* __restrict__ w,
               const float* __restrict__ enorm,
               float* __restrict__ out,
               unsigned* __restrict__ counts,
               float* __restrict__ sse,
               const int* __restrict__ rlist,
               const unsigned* __restrict__ rcnt) {
    const int lane = threadIdx.x & 63;
    const int wv   = __builtin_amdgcn_readfirstlane(threadIdx.x >> 6);  // 0..7
    const unsigned n = *rcnt;

    __shared__ float sd[8][64];
    __shared__ int   si[8][64];

    for (unsigned g = blockIdx.x; g * 64u < n; g += 256u) {
        const unsigned slot = g * 64u + (unsigned)lane;
        const bool valid = slot < n;
        const int t = valid ? rlist[slot] : 0;

        // Token row in 4 SSA vectors (now fits: 64 VGPR of x + ~30 others
        // under the 256-VGPR 2-wave/SIMD budget).
        const vf16* xp = (const vf16*)(x + (size_t)t * D);
        vf16 xa = xp[0], xb = xp[1], xc = xp[2], xd = xp[3];

        // Sx np-exact (8 accumulators, ascending blocks, pairwise tail).
        float Sx;
        {
            float r0, r1, r2, r3, r4, r5, r6, r7;
#define SQ(n) __fmul_rn(XR(n), XR(n))
            r0 = SQ(0); r1 = SQ(1); r2 = SQ(2); r3 = SQ(3);
            r4 = SQ(4); r5 = SQ(5); r6 = SQ(6); r7 = SQ(7);
#define ACC8(i)                                                           \
            r0 = __fadd_rn(r0, SQ(8*(i)+0)); r1 = __fadd_rn(r1, SQ(8*(i)+1)); \
            r2 = __fadd_rn(r2, SQ(8*(i)+2)); r3 = __fadd_rn(r3, SQ(8*(i)+3)); \
            r4 = __fadd_rn(r4, SQ(8*(i)+4)); r5 = __fadd_rn(r5, SQ(8*(i)+5)); \
            r6 = __fadd_rn(r6, SQ(8*(i)+6)); r7 = __fadd_rn(r7, SQ(8*(i)+7));
            ACC8(1) ACC8(2) ACC8(3) ACC8(4) ACC8(5) ACC8(6) ACC8(7)
            Sx = __fadd_rn(
                __fadd_rn(__fadd_rn(r0, r1), __fadd_rn(r2, r3)),
                __fadd_rn(__fadd_rn(r4, r5), __fadd_rn(r6, r7)));
#undef ACC8
#undef SQ
        }

        // np-exact scan of this wave's 128-code chunk (c ascending).
        float best = INFINITY;
        int   bidx = 0x7fffffff;
        const int c0 = wv * 128;
        for (int cc = 0; cc < 128; ++cc) {
            const int c = c0 + cc;
            const float* __restrict__ wr = w + (size_t)c * D;  // wave-uniform
            float a = 0.f;
#pragma unroll
            for (int d = 0; d < D; ++d) a = __fmaf_rn(wr[d], XR(d), a);
            float dist = __fsub_rn(__fadd_rn(Sx, enorm[c]), __fmul_rn(2.0f, a));
            bool lt = dist < best;  // strict <: first-min within chunk
            best = lt ? dist : best;
            bidx = lt ? c : bidx;
        }
        sd[wv][lane] = best;
        si[wv][lane] = bidx;
        __syncthreads();

        if (wv == 0) {
            float b  = sd[0][lane];
            int   bi = si[0][lane];
#pragma unroll
            for (int j = 1; j < 8; ++j) {
                float dj = sd[j][lane];
                bool  l  = dj < b;  // strict <: lower chunk (lower idx) wins ties
                b  = l ? dj : b;
                bi = l ? si[j][lane] : bi;
            }

            float err = 0.f;
            if (valid) {
                const float4* qr = (const float4*)(w + (size_t)bi * D);
                float4*       oq = (float4*)(out + (size_t)t * D);
#pragma unroll
                for (int i = 0; i < 16; ++i) {
                    float4 q = qr[i];
                    float e0 = q.x - XR(4 * i + 0);
                    float e1 = q.y - XR(4 * i + 1);
                    float e2 = q.z - XR(4 * i + 2);
                    float e3 = q.w - XR(4 * i + 3);
                    err = fmaf(e0, e0, err);
                    err = fmaf(e1, e1, err);
                    err = fmaf(e2, e2, err);
                    err = fmaf(e3, e3, err);
                    oq[i] = q;
                }
                out[OUT_IDX + t] = (float)bi;
                atomicAdd(&counts[bi], 1u);
            }
#pragma unroll
            for (int o = 32; o > 0; o >>= 1) err += __shfl_down(err, o, 64);
            if (lane == 0) atomicAdd(sse, err);
        }
        __syncthreads();
    }
}
#undef XR

// ---------------------------------------------------------------------------
__global__ void vq_fin(const unsigned* __restrict__ counts,
                       const float* __restrict__ sse,
                       float* __restrict__ out) {
    __shared__ float red[256];
    float s = 0.f;
    for (int k = threadIdx.x; k < K; k += 256) {
        float p = (float)counts[k] * (1.0f / (float)N_TOK);
        s += p * logf(p + 1e-10f);
    }
    red[threadIdx.x] = s;
    __syncthreads();
    for (int st = 128; st > 0; st >>= 1) {
        if (threadIdx.x < st) red[threadIdx.x] += red[threadIdx.x + st];
        __syncthreads();
    }
    if (threadIdx.x == 0) {
        out[OUT_PERP] = expf(-red[0]);
        out[OUT_LOSS] = 1.25f * (*sse) * (1.0f / 8388608.0f);  // (1+0.25)*MSE
    }
}

// ---------------------------------------------------------------------------
extern "C" void kernel_launch(void* const* d_in, const int* in_sizes, int n_in,
                              void* d_out, int out_size, void* d_ws, size_t ws_size,
                              hipStream_t stream) {
    const float* x = (const float*)d_in[0];  // [32,64,64,64] fp32
    const float* w = (const float*)d_in[1];  // [1024,64] fp32
    float* out = (float*)d_out;

    char* ws = (char*)d_ws;
    unsigned* counts = (unsigned*)(ws + 0);
    float*    enorm  = (float*)(ws + 4096);
    float*    sinit  = (float*)(ws + 8192);
    float*    sse    = (float*)(ws + 12288);
    unsigned* rcnt   = (unsigned*)(ws + 12292);
    short*    w_hi   = (short*)(ws + 16384);
    short*    w_lo   = (short*)(ws + 147456);
    int*      win    = (int*)(ws + 278528);
    int*      rlist  = (int*)(ws + 802816);

    vq_prep<<<4, 256, 0, stream>>>(w, enorm, sinit, w_hi, w_lo, counts, sse, rcnt);
    vq_screen<<<N_TOK / 128, 256, 0, stream>>>(x, sinit, w_hi, w_lo, win);
    vq_epi<<<N_TOK / 256, 256, 0, stream>>>(x, w, win, out, counts, sse, rlist, rcnt);
    vq_rescue<<<256, 512, 0, stream>>>(x, w, enorm, out, counts, sse, rlist, rcnt);
    vq_fin<<<1, 256, 0, stream>>>(counts, sse, out);
}